// Round 6
// baseline (302.625 us; speedup 1.0000x reference)
//
#include <hip/hip_runtime.h>
#include <hip/hip_bf16.h>
#include <stdint.h>

// B=4, T=2048, K(=D)=128, H=8, KS=5, DIL=2, PAD=8, M=B*H=32
// scale = 128^0.25 ; inv = 0.29730177875068026

typedef __attribute__((ext_vector_type(8))) short bf16x8;
typedef __attribute__((ext_vector_type(4))) float f32x4;
typedef __attribute__((ext_vector_type(4))) int   i32x4;
typedef unsigned short ushort_t;

__device__ __forceinline__ unsigned short f2bf(float x){
  union{float f; unsigned u;} v; v.f = x;
  unsigned r = v.u + 0x7FFFu + ((v.u >> 16) & 1u);   // RNE
  return (unsigned short)(r >> 16);
}
__device__ __forceinline__ float silu_f(float x){ return x / (1.f + __expf(-x)); }

__device__ __forceinline__ int cvt_pk_bf16(float lo, float hi){
  int r;
  asm("v_cvt_pk_bf16_f32 %0, %1, %2" : "=v"(r) : "v"(lo), "v"(hi));
  return r;
}

__device__ __forceinline__ void async_cp16(void* lds, const void* g){
  __builtin_amdgcn_global_load_lds(
      (const __attribute__((address_space(1))) unsigned int*)g,
      (__attribute__((address_space(3))) unsigned int*)lds, 16, 0, 0);
}

// ---------------------------------------------------------------------------
// Weight prep: W2p[(qk*8+h)*128+d][r] = bf16(W{q,k}[d*8+h][r]), r = ci*5+j.
// n in [2048,3072): Wvp[co][ci] = bf16(Wv).  n in [3072,3200): Wub[j][hd].
// ---------------------------------------------------------------------------
__global__ __launch_bounds__(256) void wprep(const float* __restrict__ Wq,
                                             const float* __restrict__ Wk,
                                             const float* __restrict__ Wv,
                                             const float* __restrict__ Wu,
                                             ushort_t* __restrict__ W2p,
                                             ushort_t* __restrict__ Wvp,
                                             ushort_t* __restrict__ Wub){
  int n = blockIdx.x;
  int tid = threadIdx.x;
  if (n < 2048){
    int qk = n >> 10, h = (n >> 7) & 7, d = n & 127;
    const float* src = (qk ? Wk : Wq) + (size_t)(d*8 + h)*640;
    for (int r = tid; r < 640; r += 256) W2p[(size_t)n*640 + r] = f2bf(src[r]);
  } else if (n < 3072){
    int co = n - 2048;
    for (int r = tid; r < 128; r += 256)
      Wvp[(size_t)co*128 + r] = f2bf(Wv[(size_t)co*128 + r]);
  } else {
    int j = n - 3072;
    for (int r = tid; r < 1024; r += 256)
      Wub[(size_t)j*1024 + r] = f2bf(Wu[(size_t)j*1024 + r]);
  }
}

// ---------------------------------------------------------------------------
// im2col: Xim[b*2048+t][ci*5+j] = bf16(x[b][t-8+2j][ci]); Xv = bf16(x) rows.
// ---------------------------------------------------------------------------
__global__ __launch_bounds__(256) void im2col(const float* __restrict__ x,
                                              ushort_t* __restrict__ Xim,
                                              ushort_t* __restrict__ Xv){
  __shared__ float xs[72*132];
  int b = blockIdx.y, t0 = blockIdx.x * 64;
  int tid = threadIdx.x;
  for (int idx = tid; idx < 72*32; idx += 256){
    int tt = idx >> 5, c4 = (idx & 31) * 4;
    int gt = t0 - 8 + tt;
    float4 v; v.x = v.y = v.z = v.w = 0.f;
    if (gt >= 0) v = *(const float4*)&x[((size_t)(b*2048 + gt))*128 + c4];
    *(float4*)&xs[tt*132 + c4] = v;
  }
  __syncthreads();
  for (int trow = 0; trow < 64; trow++){
    size_t obase = (size_t)(b*2048 + t0 + trow);
    for (int r = tid; r < 640; r += 256){
      int ci = r / 5, j = r - ci*5;
      Xim[obase*640 + r] = f2bf(xs[(trow + 2*j)*132 + ci]);
    }
    for (int r = tid; r < 128; r += 256)
      Xv[obase*128 + r] = f2bf(xs[(trow + 8)*132 + r]);
  }
}

// ---------------------------------------------------------------------------
// gemm_qk: C^T[t][n] = sum_r Xim[t][r] * W2p[n][r],  K=640, tile 128x128 BK=32.
// ---------------------------------------------------------------------------
__global__ __launch_bounds__(256) void gemm_qk(
    const ushort_t* __restrict__ Xim,   // [8192][640]
    const ushort_t* __restrict__ W2p,   // [2048][640]
    const float* __restrict__ bq, const float* __restrict__ bk,
    ushort_t* __restrict__ Q2, ushort_t* __restrict__ K2)
{
  __shared__ ushort_t As[128*32] __attribute__((aligned(16)));
  __shared__ ushort_t Bs[128*32] __attribute__((aligned(16)));
  int n0  = blockIdx.x * 128;
  int bt0 = blockIdx.y * 128;
  int tid = threadIdx.x;
  int w = tid >> 6, ln = tid & 63;
  int lc = ln & 15, lg = ln >> 4;
  int mi = (w & 1) * 64, nj = (w >> 1) * 64;

  int srow = ln >> 2;
  int kseg = (ln & 3) * 8;

  f32x4 acc[4][4];
  #pragma unroll
  for (int si = 0; si < 4; si++)
    #pragma unroll
    for (int sj = 0; sj < 4; sj++) acc[si][sj] = (f32x4){0.f,0.f,0.f,0.f};

  const ushort_t* gA = Xim + (size_t)(bt0 + w*32 + srow)*640 + kseg;
  const ushort_t* gB = W2p + (size_t)(n0  + w*32 + srow)*640 + kseg;

  for (int kk = 0; kk < 20; kk++){
    int r0 = kk * 32;
    __syncthreads();
    async_cp16(&As[w*1024],        gA + r0);
    async_cp16(&As[w*1024 + 512],  gA + r0 + 16*640);
    async_cp16(&Bs[w*1024],        gB + r0);
    async_cp16(&Bs[w*1024 + 512],  gB + r0 + 16*640);
    __syncthreads();
    bf16x8 af[4], bfr[4];
    #pragma unroll
    for (int si = 0; si < 4; si++)
      af[si] = *(const bf16x8*)&As[(mi + 16*si + lc)*32 + 8*lg];
    #pragma unroll
    for (int sj = 0; sj < 4; sj++)
      bfr[sj] = *(const bf16x8*)&Bs[(nj + 16*sj + lc)*32 + 8*lg];
    #pragma unroll
    for (int si = 0; si < 4; si++)
      #pragma unroll
      for (int sj = 0; sj < 4; sj++)
        acc[si][sj] = __builtin_amdgcn_mfma_f32_16x16x32_bf16(af[si], bfr[sj],
                                                              acc[si][sj], 0,0,0);
  }

  const float inv_scale = 0.29730177875068026f;
  int qk = n0 >> 10, h = (n0 >> 7) & 7;
  const float* bias = qk ? bk : bq;
  ushort_t* dst = qk ? K2 : Q2;
  float bv[4];
  #pragma unroll
  for (int sj = 0; sj < 4; sj++) bv[sj] = bias[(nj + 16*sj + lc)*8 + h];

  #pragma unroll
  for (int si = 0; si < 4; si++){
    int btb = bt0 + mi + 16*si + 4*lg;
    #pragma unroll
    for (int r = 0; r < 4; r++){
      int t = btb + r;
      int bb = t >> 11, tl = t & 2047;
      size_t rowoff = ((size_t)(bb*8 + (tl >> 8))*2048 + (tl & 255)*8 + h)*128;
      #pragma unroll
      for (int sj = 0; sj < 4; sj++){
        int d = nj + 16*sj + lc;
        dst[rowoff + d] = f2bf(silu_f(acc[si][sj][r] + bv[sj]) * inv_scale);
      }
    }
  }
}

// ---------------------------------------------------------------------------
// gemm_v: C^T[t][co] = sum_ci Xv[t][ci] * Wvp[co][ci], K=128.
// ---------------------------------------------------------------------------
__global__ __launch_bounds__(256) void gemm_v(
    const ushort_t* __restrict__ Xv,    // [8192][128]
    const ushort_t* __restrict__ Wvp,   // [1024][128]
    ushort_t* __restrict__ V2t)
{
  __shared__ ushort_t As[128*32] __attribute__((aligned(16)));
  __shared__ ushort_t Bs[128*32] __attribute__((aligned(16)));
  int n0  = blockIdx.x * 128;
  int bt0 = blockIdx.y * 128;
  int tid = threadIdx.x;
  int w = tid >> 6, ln = tid & 63;
  int lc = ln & 15, lg = ln >> 4;
  int mi = (w & 1) * 64, nj = (w >> 1) * 64;
  int srow = ln >> 2;
  int kseg = (ln & 3) * 8;

  f32x4 acc[4][4];
  #pragma unroll
  for (int si = 0; si < 4; si++)
    #pragma unroll
    for (int sj = 0; sj < 4; sj++) acc[si][sj] = (f32x4){0.f,0.f,0.f,0.f};

  const ushort_t* gA = Xv  + (size_t)(bt0 + w*32 + srow)*128 + kseg;
  const ushort_t* gB = Wvp + (size_t)(n0  + w*32 + srow)*128 + kseg;

  for (int kk = 0; kk < 4; kk++){
    int r0 = kk * 32;
    __syncthreads();
    async_cp16(&As[w*1024],        gA + r0);
    async_cp16(&As[w*1024 + 512],  gA + r0 + 16*128);
    async_cp16(&Bs[w*1024],        gB + r0);
    async_cp16(&Bs[w*1024 + 512],  gB + r0 + 16*128);
    __syncthreads();
    bf16x8 af[4], bfr[4];
    #pragma unroll
    for (int si = 0; si < 4; si++)
      af[si] = *(const bf16x8*)&As[(mi + 16*si + lc)*32 + 8*lg];
    #pragma unroll
    for (int sj = 0; sj < 4; sj++)
      bfr[sj] = *(const bf16x8*)&Bs[(nj + 16*sj + lc)*32 + 8*lg];
    #pragma unroll
    for (int si = 0; si < 4; si++)
      #pragma unroll
      for (int sj = 0; sj < 4; sj++)
        acc[si][sj] = __builtin_amdgcn_mfma_f32_16x16x32_bf16(af[si], bfr[sj],
                                                              acc[si][sj], 0,0,0);
  }

  #pragma unroll
  for (int si = 0; si < 4; si++){
    int btb = bt0 + mi + 16*si + 4*lg;
    #pragma unroll
    for (int r = 0; r < 4; r++){
      int t = btb + r;
      int bb = t >> 11, tl = t & 2047;
      int mm = bb*8 + (tl >> 8);
      int tpb = (tl & 255)*8;
      #pragma unroll
      for (int sj = 0; sj < 4; sj++){
        int co = n0 + nj + 16*sj + lc;
        int d = co >> 3, hh = co & 7;
        V2t[((size_t)mm*128 + d)*2048 + tpb + hh] = f2bf(silu_f(acc[si][sj][r]));
      }
    }
  }
}

// ---------------------------------------------------------------------------
// Flash attention v5: LDS-FREE. 2048 one-wave blocks, each owns one 32-q
// slice of one m. K/V fragments loaded directly global->VGPR (16B/lane,
// coalesced), software-pipelined: K(step+1) prefetched during step, V(step)
// issued before QK and consumed after QK+exp (~300cyc cover). No barriers,
// no LDS; occupancy capped only by VGPRs (launch_bounds(64,2) -> 8 waves/CU).
// Longest-slice-first order + per-XCD m grouping (4 m x 1MB K+V = L2-resident).
// No online max (bounded inputs; exp(s-8) w/ clamp). 32-s tiles.
// ---------------------------------------------------------------------------
__global__ __launch_bounds__(64, 2) void attn(
    const ushort_t* __restrict__ Q2,   // [32][2048][128]
    const ushort_t* __restrict__ K2,   // [32][2048][128]
    const ushort_t* __restrict__ V2t,  // [32][128][2048]
    ushort_t* __restrict__ O2)         // [8192][1024] bf16
{
  int bid = blockIdx.x;                 // 2048
  int seq = bid >> 3;                   // 0..255 per XCD
  int m   = 4*(bid & 7) + (seq & 3);    // 4 m-slices per XCD -> L2-resident K/V
  int i   = 63 - (seq >> 2);            // q-slice index, longest first
  int q0  = 32*i;
  int nt  = i + 1;                      // number of 32-s tiles
  int l = threadIdx.x;
  int lc = l & 15, lg = l >> 4;

  const size_t mQ = (size_t)m * 2048;
  const ushort_t* kp = K2  + mQ*128 + (size_t)lc*128 + 8*lg;          // +(s0+st*16)*128+32c
  const ushort_t* vp = V2t + (size_t)m*128*2048 + (size_t)lc*2048 + 8*lg; // +dt*16*2048+s0
  int hb = m & 7, bI = m >> 3;

  int psel[4];
  #pragma unroll
  for (int w2 = 0; w2 < 4; w2++)
    psel[w2] = ((((2*(lg & 1) + (w2 >> 1)) << 4) | lc) << 2);

  bf16x8 qfrag[2][4];
  #pragma unroll
  for (int s01 = 0; s01 < 2; s01++){
    const ushort_t* qp = Q2 + (mQ + q0 + s01*16 + lc)*128 + 8*lg;
    #pragma unroll
    for (int c = 0; c < 4; c++) qfrag[s01][c] = *(const bf16x8*)(qp + 32*c);
  }
  f32x4 oacc[2][8];
  #pragma unroll
  for (int s01 = 0; s01 < 2; s01++)
    #pragma unroll
    for (int dt = 0; dt < 8; dt++) oacc[s01][dt] = (f32x4){0.f,0.f,0.f,0.f};
  float lrow[2] = {0.f, 0.f};

  const float LOG2E = 1.4426950408889634f;
  const float EOFF  = -11.541560327111707f;   // -8 * log2(e)

  i32x4 ka[8], kb[8], vv[8];

  auto loadK = [&](i32x4* dst, int s0){
    #pragma unroll
    for (int st = 0; st < 2; st++)
      #pragma unroll
      for (int c = 0; c < 4; c++)
        dst[st*4 + c] = *(const i32x4*)(kp + (size_t)(s0 + st*16)*128 + 32*c);
  };
  auto loadV = [&](int s0){
    #pragma unroll
    for (int dt = 0; dt < 8; dt++)
      vv[dt] = *(const i32x4*)(vp + (size_t)dt*16*2048 + s0);
  };

  auto body = [&](const i32x4* kin, i32x4* kout, int s0, bool last){
    int spre = s0 + 32; if (spre > 2016) spre = 2016;   // clamped prefetch
    loadK(kout, spre);
    loadV(s0);

    // QK: S^T subtiles, both q-sets share each K frag
    f32x4 sacc[2][2];
    #pragma unroll
    for (int st = 0; st < 2; st++){
      f32x4 a0 = (f32x4){0.f,0.f,0.f,0.f};
      f32x4 a1 = (f32x4){0.f,0.f,0.f,0.f};
      #pragma unroll
      for (int c = 0; c < 4; c++){
        bf16x8 kf = *(const bf16x8*)&kin[st*4 + c];
        a0 = __builtin_amdgcn_mfma_f32_16x16x32_bf16(kf, qfrag[0][c], a0, 0, 0, 0);
        a1 = __builtin_amdgcn_mfma_f32_16x16x32_bf16(kf, qfrag[1][c], a1, 0, 0, 0);
      }
      sacc[0][st] = a0; sacc[1][st] = a1;
    }
    if (last){
      #pragma unroll
      for (int s01 = 0; s01 < 2; s01++){
        int qg = q0 + s01*16 + lc;
        #pragma unroll
        for (int st = 0; st < 2; st++)
          #pragma unroll
          for (int r = 0; r < 4; r++){
            int sg = s0 + st*16 + 4*lg + r;
            if (sg > qg) sacc[s01][st][r] = -1e30f;
          }
      }
    }
    // p = exp(s-8) in place
    #pragma unroll
    for (int s01 = 0; s01 < 2; s01++)
      #pragma unroll
      for (int st = 0; st < 2; st++)
        #pragma unroll
        for (int r = 0; r < 4; r++){
          float sv = fminf(fmaf(sacc[s01][st][r], LOG2E, EOFF), 108.f);
          float pv = __builtin_amdgcn_exp2f(sv);
          sacc[s01][st][r] = pv;
          lrow[s01] += pv;
        }
    // PV
    union { int i[4]; bf16x8 v; } bfr[2];
    #pragma unroll
    for (int s01 = 0; s01 < 2; s01++){
      int pk0[2], pk1[2];
      #pragma unroll
      for (int pa = 0; pa < 2; pa++){
        pk0[pa] = cvt_pk_bf16(sacc[s01][0][2*pa], sacc[s01][0][2*pa+1]);
        pk1[pa] = cvt_pk_bf16(sacc[s01][1][2*pa], sacc[s01][1][2*pa+1]);
      }
      #pragma unroll
      for (int w2 = 0; w2 < 4; w2++){
        int v0 = __builtin_amdgcn_ds_bpermute(psel[w2], pk0[w2 & 1]);
        int v1 = __builtin_amdgcn_ds_bpermute(psel[w2], pk1[w2 & 1]);
        bfr[s01].i[w2] = (lg >> 1) ? v1 : v0;
      }
    }
    #pragma unroll
    for (int dt = 0; dt < 8; dt++){
      bf16x8 vf = *(const bf16x8*)&vv[dt];
      oacc[0][dt] = __builtin_amdgcn_mfma_f32_16x16x32_bf16(vf, bfr[0].v, oacc[0][dt], 0, 0, 0);
      oacc[1][dt] = __builtin_amdgcn_mfma_f32_16x16x32_bf16(vf, bfr[1].v, oacc[1][dt], 0, 0, 0);
    }
  };

  loadK(ka, 0);
  int step = 0;
  for (; step + 2 <= nt; step += 2){
    body(ka, kb, 32*step,       false);
    body(kb, ka, 32*(step + 1), step + 1 == nt - 1);
  }
  if (step < nt) body(ka, kb, 32*step, true);

  // epilogue: normalize, pack, store
  #pragma unroll
  for (int s01 = 0; s01 < 2; s01++){
    float lt = lrow[s01];
    lt += __shfl_xor(lt, 16);
    lt += __shfl_xor(lt, 32);
    float invl = 1.f / lt;
    size_t obase = ((size_t)(bI*2048 + q0 + s01*16 + lc))*1024 + hb*128 + 4*lg;
    #pragma unroll
    for (int dt = 0; dt < 8; dt++){
      uint2 val;
      val.x = (unsigned)cvt_pk_bf16(oacc[s01][dt][0]*invl, oacc[s01][dt][1]*invl);
      val.y = (unsigned)cvt_pk_bf16(oacc[s01][dt][2]*invl, oacc[s01][dt][3]*invl);
      *(uint2*)&O2[obase + 16*dt] = val;
    }
  }
}

// ---------------------------------------------------------------------------
// finalmm (MFMA): out[bt][j] = silu(bu[j] + sum_hd O2[bt][hd]*Wub[j][hd]).
// ---------------------------------------------------------------------------
__global__ __launch_bounds__(256) void finalmm(
    const ushort_t* __restrict__ O2,    // [8192][1024] bf16
    const ushort_t* __restrict__ Wub,   // [128][1024] bf16
    const float* __restrict__ bu,
    float* __restrict__ out)            // [8192][128]
{
  __shared__ ushort_t As[64*32]  __attribute__((aligned(16)));   // 4 KB
  __shared__ ushort_t Bs[128*32] __attribute__((aligned(16)));   // 8 KB
  int bt0 = blockIdx.x * 64;
  int tid = threadIdx.x;
  int w = tid >> 6, ln = tid & 63;
  int lc = ln & 15, lg = ln >> 4;
  int nj = w * 32;
  int srow = ln >> 2;
  int kseg = (ln & 3) * 8;

  f32x4 acc[4][2];
  #pragma unroll
  for (int si = 0; si < 4; si++)
    #pragma unroll
    for (int sj = 0; sj < 2; sj++) acc[si][sj] = (f32x4){0.f,0.f,0.f,0.f};

  const ushort_t* gA = O2  + (size_t)(bt0 + w*16 + srow)*1024 + kseg;
  const ushort_t* gB = Wub + (size_t)(w*32 + srow)*1024 + kseg;

  for (int kk = 0; kk < 32; kk++){
    int r0 = kk * 32;
    __syncthreads();
    async_cp16(&As[w*512],        gA + r0);
    async_cp16(&Bs[w*1024],       gB + r0);
    async_cp16(&Bs[w*1024 + 512], gB + r0 + 16*1024);
    __syncthreads();
    bf16x8 af[4], bfr[2];
    #pragma unroll
    for (int si = 0; si < 4; si++)
      af[si] = *(const bf16x8*)&As[(16*si + lc)*32 + 8*lg];
    #pragma unroll
    for (int sj = 0; sj < 2; sj++)
      bfr[sj] = *(const bf16x8*)&Bs[(nj + 16*sj + lc)*32 + 8*lg];
    #pragma unroll
    for (int si = 0; si < 4; si++)
      #pragma unroll
      for (int sj = 0; sj < 2; sj++)
        acc[si][sj] = __builtin_amdgcn_mfma_f32_16x16x32_bf16(af[si], bfr[sj],
                                                              acc[si][sj], 0,0,0);
  }

  float bv[2];
  #pragma unroll
  for (int sj = 0; sj < 2; sj++) bv[sj] = bu[nj + 16*sj + lc];
  #pragma unroll
  for (int si = 0; si < 4; si++)
    #pragma unroll
    for (int r = 0; r < 4; r++){
      int t = bt0 + 16*si + 4*lg + r;
      #pragma unroll
      for (int sj = 0; sj < 2; sj++)
        out[(size_t)t*128 + nj + 16*sj + lc] = silu_f(acc[si][sj][r] + bv[sj]);
    }
}

// ---------------------------------------------------------------------------
extern "C" void kernel_launch(void* const* d_in, const int* in_sizes, int n_in,
                              void* d_out, int out_size, void* d_ws, size_t ws_size,
                              hipStream_t stream) {
  const float* x  = (const float*)d_in[0];
  const float* Wq = (const float*)d_in[1];
  const float* bq = (const float*)d_in[2];
  const float* Wk = (const float*)d_in[3];
  const float* bk = (const float*)d_in[4];
  const float* Wv = (const float*)d_in[5];
  const float* Wu = (const float*)d_in[6];
  const float* bu = (const float*)d_in[7];
  float* out = (float*)d_out;

  char* ws = (char*)d_ws;
  ushort_t* Q2  = (ushort_t*)(ws + 0);            // 16 MB
  ushort_t* K2  = (ushort_t*)(ws + 16777216);     // 16 MB
  ushort_t* V2t = (ushort_t*)(ws + 33554432);     // 16 MB
  ushort_t* O2  = (ushort_t*)(ws + 50331648);     // 16 MB (bf16 [8192][1024])
  ushort_t* Xim = (ushort_t*)(ws + 67108864);     // 10.5 MB
  ushort_t* Xv  = (ushort_t*)(ws + 77594624);     // 2 MB
  ushort_t* W2p = (ushort_t*)(ws + 79691776);     // 2.5 MB
  ushort_t* Wvp = (ushort_t*)(ws + 82313216);     // 0.25 MB
  ushort_t* Wub = (ushort_t*)(ws + 82575360);     // 0.25 MB

  wprep<<<dim3(3200, 1, 1), 256, 0, stream>>>(Wq, Wk, Wv, Wu, W2p, Wvp, Wub);
  im2col<<<dim3(32, 4, 1), 256, 0, stream>>>(x, Xim, Xv);

  gemm_qk<<<dim3(16, 64, 1), 256, 0, stream>>>(Xim, W2p, bq, bk, Q2, K2);
  gemm_v<<<dim3(8, 64, 1), 256, 0, stream>>>(Xv, Wvp, V2t);

  attn<<<dim3(2048, 1, 1), 64, 0, stream>>>(Q2, K2, V2t, O2);
  finalmm<<<dim3(128, 1, 1), 256, 0, stream>>>(O2, Wub, bu, out);
}

// Round 8
// 216.011 us; speedup vs baseline: 1.4010x; 1.4010x over previous
//
#include <hip/hip_runtime.h>
#include <hip/hip_bf16.h>
#include <stdint.h>

// B=4, T=2048, K(=D)=128, H=8, KS=5, DIL=2, PAD=8, M=B*H=32
// scale = 128^0.25 ; inv = 0.29730177875068026

typedef __attribute__((ext_vector_type(8))) short bf16x8;
typedef __attribute__((ext_vector_type(4))) float f32x4;
typedef __attribute__((ext_vector_type(4))) int   i32x4;
typedef unsigned short ushort_t;

__device__ __forceinline__ unsigned short f2bf(float x){
  union{float f; unsigned u;} v; v.f = x;
  unsigned r = v.u + 0x7FFFu + ((v.u >> 16) & 1u);   // RNE
  return (unsigned short)(r >> 16);
}
__device__ __forceinline__ float silu_f(float x){ return x / (1.f + __expf(-x)); }

__device__ __forceinline__ int cvt_pk_bf16(float lo, float hi){
  int r;
  asm("v_cvt_pk_bf16_f32 %0, %1, %2" : "=v"(r) : "v"(lo), "v"(hi));
  return r;
}

__device__ __forceinline__ void async_cp16(void* lds, const void* g){
  __builtin_amdgcn_global_load_lds(
      (const __attribute__((address_space(1))) unsigned int*)g,
      (__attribute__((address_space(3))) unsigned int*)lds, 16, 0, 0);
}

// ---------------------------------------------------------------------------
// Weight prep. K-dim order for the qk GEMM is r' = j*128 + ci (so the
// A-matrix is x itself with a row offset — no materialized im2col).
//   n in [0,2048):   W2p[(qk*8+h)*128+d][j*128+ci] = bf16(W{q,k}[d*8+h][ci*5+j])
//   n in [2048,3072): Wvp[co][ci] = bf16(Wv[co][ci])
//   n in [3072,3200): Wub[j][hd]  = bf16(Wu[j][hd])
// ---------------------------------------------------------------------------
__global__ __launch_bounds__(256) void wprep(const float* __restrict__ Wq,
                                             const float* __restrict__ Wk,
                                             const float* __restrict__ Wv,
                                             const float* __restrict__ Wu,
                                             ushort_t* __restrict__ W2p,
                                             ushort_t* __restrict__ Wvp,
                                             ushort_t* __restrict__ Wub){
  int n = blockIdx.x;
  int tid = threadIdx.x;
  if (n < 2048){
    int qk = n >> 10, h = (n >> 7) & 7, d = n & 127;
    const float* src = (qk ? Wk : Wq) + (size_t)(d*8 + h)*640;
    for (int rp = tid; rp < 640; rp += 256){
      int j = rp >> 7, ci = rp & 127;
      W2p[(size_t)n*640 + rp] = f2bf(src[ci*5 + j]);
    }
  } else if (n < 3072){
    int co = n - 2048;
    for (int r = tid; r < 128; r += 256)
      Wvp[(size_t)co*128 + r] = f2bf(Wv[(size_t)co*128 + r]);
  } else {
    int j = n - 3072;
    for (int r = tid; r < 1024; r += 256)
      Wub[(size_t)j*1024 + r] = f2bf(Wu[(size_t)j*1024 + r]);
  }
}

// ---------------------------------------------------------------------------
// xprep: Xpad[b][rt][ci] = (rt < 8) ? 0 : bf16(x[b][rt-8][ci]).  [4][2056][128]
// ---------------------------------------------------------------------------
__global__ __launch_bounds__(256) void xprep(const float* __restrict__ x,
                                             ushort_t* __restrict__ Xpad){
  int b  = blockIdx.y;
  int rt = blockIdx.x * 2 + (threadIdx.x >> 7);
  int ci = threadIdx.x & 127;
  int t  = rt - 8;
  ushort_t v = 0;
  if (t >= 0) v = f2bf(x[((size_t)(b*2048 + t))*128 + ci]);
  Xpad[((size_t)(b*2056 + rt))*128 + ci] = v;
}

// ---------------------------------------------------------------------------
// gemm_qk: C^T[t][n] = sum_{j,ci} Xpad[b][tl+2j][ci] * W2p[n][j*128+ci],
// K=640 (r'=j*128+ci), tile 128x128 BK=32. Fused bias+silu+scale epilogue,
// scatter to Q2/K2 scrambled layout [m][tp][d].
// ---------------------------------------------------------------------------
__global__ __launch_bounds__(256) void gemm_qk(
    const ushort_t* __restrict__ Xpad,  // [4][2056][128]
    const ushort_t* __restrict__ W2p,   // [2048][640]
    const float* __restrict__ bq, const float* __restrict__ bk,
    ushort_t* __restrict__ Q2, ushort_t* __restrict__ K2)
{
  __shared__ ushort_t As[128*32] __attribute__((aligned(16)));
  __shared__ ushort_t Bs[128*32] __attribute__((aligned(16)));
  int n0  = blockIdx.x * 128;
  int bt0 = blockIdx.y * 128;
  int tid = threadIdx.x;
  int w = tid >> 6, ln = tid & 63;
  int lc = ln & 15, lg = ln >> 4;
  int mi = (w & 1) * 64, nj = (w >> 1) * 64;

  int srow = ln >> 2;
  int kseg = (ln & 3) * 8;

  f32x4 acc[4][4];
  #pragma unroll
  for (int si = 0; si < 4; si++)
    #pragma unroll
    for (int sj = 0; sj < 4; sj++) acc[si][sj] = (f32x4){0.f,0.f,0.f,0.f};

  int b = bt0 >> 11, tl0 = bt0 & 2047;
  const ushort_t* gA = Xpad + (size_t)(b*2056 + tl0 + w*32 + srow)*128 + kseg;
  const ushort_t* gB = W2p + (size_t)(n0  + w*32 + srow)*640 + kseg;

  for (int kk = 0; kk < 20; kk++){
    int j = kk >> 2, ci0 = (kk & 3) * 32;
    int r0 = kk * 32;
    const ushort_t* a0 = gA + (size_t)(2*j)*128 + ci0;
    __syncthreads();
    async_cp16(&As[w*1024],        a0);
    async_cp16(&As[w*1024 + 512],  a0 + 16*128);
    async_cp16(&Bs[w*1024],        gB + r0);
    async_cp16(&Bs[w*1024 + 512],  gB + r0 + 16*640);
    __syncthreads();
    bf16x8 af[4], bfr[4];
    #pragma unroll
    for (int si = 0; si < 4; si++)
      af[si] = *(const bf16x8*)&As[(mi + 16*si + lc)*32 + 8*lg];
    #pragma unroll
    for (int sj = 0; sj < 4; sj++)
      bfr[sj] = *(const bf16x8*)&Bs[(nj + 16*sj + lc)*32 + 8*lg];
    #pragma unroll
    for (int si = 0; si < 4; si++)
      #pragma unroll
      for (int sj = 0; sj < 4; sj++)
        acc[si][sj] = __builtin_amdgcn_mfma_f32_16x16x32_bf16(af[si], bfr[sj],
                                                              acc[si][sj], 0,0,0);
  }

  const float inv_scale = 0.29730177875068026f;
  int qk = n0 >> 10, h = (n0 >> 7) & 7;
  const float* bias = qk ? bk : bq;
  ushort_t* dst = qk ? K2 : Q2;
  float bv[4];
  #pragma unroll
  for (int sj = 0; sj < 4; sj++) bv[sj] = bias[(nj + 16*sj + lc)*8 + h];

  #pragma unroll
  for (int si = 0; si < 4; si++){
    int btb = bt0 + mi + 16*si + 4*lg;
    #pragma unroll
    for (int r = 0; r < 4; r++){
      int t = btb + r;
      int bb = t >> 11, tl = t & 2047;
      size_t rowoff = ((size_t)(bb*8 + (tl >> 8))*2048 + (tl & 255)*8 + h)*128;
      #pragma unroll
      for (int sj = 0; sj < 4; sj++){
        int d = nj + 16*sj + lc;
        dst[rowoff + d] = f2bf(silu_f(acc[si][sj][r] + bv[sj]) * inv_scale);
      }
    }
  }
}

// ---------------------------------------------------------------------------
// gemm_v: C^T[t][co] = sum_ci Xpad[b][tl+8][ci] * Wvp[co][ci], K=128.
// ---------------------------------------------------------------------------
__global__ __launch_bounds__(256) void gemm_v(
    const ushort_t* __restrict__ Xpad,  // [4][2056][128]
    const ushort_t* __restrict__ Wvp,   // [1024][128]
    ushort_t* __restrict__ V2t)
{
  __shared__ ushort_t As[128*32] __attribute__((aligned(16)));
  __shared__ ushort_t Bs[128*32] __attribute__((aligned(16)));
  int n0  = blockIdx.x * 128;
  int bt0 = blockIdx.y * 128;
  int tid = threadIdx.x;
  int w = tid >> 6, ln = tid & 63;
  int lc = ln & 15, lg = ln >> 4;
  int mi = (w & 1) * 64, nj = (w >> 1) * 64;
  int srow = ln >> 2;
  int kseg = (ln & 3) * 8;

  f32x4 acc[4][4];
  #pragma unroll
  for (int si = 0; si < 4; si++)
    #pragma unroll
    for (int sj = 0; sj < 4; sj++) acc[si][sj] = (f32x4){0.f,0.f,0.f,0.f};

  int b = bt0 >> 11, tl0 = bt0 & 2047;
  const ushort_t* gA = Xpad + (size_t)(b*2056 + 8 + tl0 + w*32 + srow)*128 + kseg;
  const ushort_t* gB = Wvp  + (size_t)(n0 + w*32 + srow)*128 + kseg;

  for (int kk = 0; kk < 4; kk++){
    int r0 = kk * 32;
    __syncthreads();
    async_cp16(&As[w*1024],        gA + r0);
    async_cp16(&As[w*1024 + 512],  gA + r0 + 16*128);
    async_cp16(&Bs[w*1024],        gB + r0);
    async_cp16(&Bs[w*1024 + 512],  gB + r0 + 16*128);
    __syncthreads();
    bf16x8 af[4], bfr[4];
    #pragma unroll
    for (int si = 0; si < 4; si++)
      af[si] = *(const bf16x8*)&As[(mi + 16*si + lc)*32 + 8*lg];
    #pragma unroll
    for (int sj = 0; sj < 4; sj++)
      bfr[sj] = *(const bf16x8*)&Bs[(nj + 16*sj + lc)*32 + 8*lg];
    #pragma unroll
    for (int si = 0; si < 4; si++)
      #pragma unroll
      for (int sj = 0; sj < 4; sj++)
        acc[si][sj] = __builtin_amdgcn_mfma_f32_16x16x32_bf16(af[si], bfr[sj],
                                                              acc[si][sj], 0,0,0);
  }

  #pragma unroll
  for (int si = 0; si < 4; si++){
    int btb = bt0 + mi + 16*si + 4*lg;
    #pragma unroll
    for (int r = 0; r < 4; r++){
      int t = btb + r;
      int bb = t >> 11, tl = t & 2047;
      int mm = bb*8 + (tl >> 8);
      int tpb = (tl & 255)*8;
      #pragma unroll
      for (int sj = 0; sj < 4; sj++){
        int co = n0 + nj + 16*sj + lc;
        int d = co >> 3, hh = co & 7;
        V2t[((size_t)mm*128 + d)*2048 + tpb + hh] = f2bf(silu_f(acc[si][sj][r]));
      }
    }
  }
}

// ---------------------------------------------------------------------------
// Flash attention v6 = best-known v3 structure + bf16 O2 epilogue.
// 256-thr blocks (4 waves x 16 q), paired causal blocks (i,31-i) -> uniform
// 33 tile-units; 64-s tiles; dbuf global_load_lds staging w/ vmcnt(8);
// no online max (bounded inputs; exp(s-8) w/ clamp); deferred lrow reduce.
// Output bf16 O2[bI*2048+tau][hb*128+delta] row-major for MFMA finalmm.
// ---------------------------------------------------------------------------
__global__ __launch_bounds__(256) void attn(
    const ushort_t* __restrict__ Q2,   // [32][2048][128]
    const ushort_t* __restrict__ K2,   // [32][2048][128]
    const ushort_t* __restrict__ V2t,  // [32][128][2048]
    ushort_t* __restrict__ O2)         // [8192][1024] bf16
{
  __shared__ i32x4 kbuf[2][1024];      // [buf][(st*4+c)*64 + lane]  16KB each
  __shared__ i32x4 vbuf[2][1024];      // [buf][(dt*2+ks)*64 + lane] 16KB each

  int bid = blockIdx.x;                      // 512 blocks
  int m   = ((bid & 7) << 2) | ((bid >> 3) & 3);  // XCD-L2 locality swizzle
  int ip  = bid >> 5;                        // pair index 0..15
  int tid = threadIdx.x;
  int w = tid >> 6, l = tid & 63;
  int lc = l & 15, lg = l >> 4;

  int iA = 31 - ip, iB = ip;
  int ntA = iA + 1;
  const int nt = 33;

  const size_t mQ = (size_t)m * 2048;
  const ushort_t* Kbase = K2  + mQ * 128;
  const ushort_t* Vbase = V2t + (size_t)m * 128 * 2048;
  int hb = m & 7, bI = m >> 3;

  int psel[4];
  #pragma unroll
  for (int w2 = 0; w2 < 4; w2++)
    psel[w2] = ((((2*(lg & 1) + (w2 >> 1)) << 4) | lc) << 2);

  auto stage = [&](int s0, int bsel){
    const ushort_t* krow = Kbase + (size_t)(s0 + w*16 + lc)*128 + 8*lg;
    #pragma unroll
    for (int c = 0; c < 4; c++)
      async_cp16(&kbuf[bsel][(w*4 + c)*64], krow + 32*c);
    #pragma unroll
    for (int j = 0; j < 4; j++){
      int dt = w*2 + (j >> 1);
      const ushort_t* vrow = Vbase + (size_t)(dt*16 + lc)*2048
                             + s0 + (j & 1)*32 + 8*lg;
      async_cp16(&vbuf[bsel][(w*4 + j)*64], vrow);
    }
  };

  int qb = iA*64 + w*16;
  bf16x8 qfrag[4];
  {
    const ushort_t* qp = Q2 + (mQ + qb + lc)*128 + 8*lg;
    #pragma unroll
    for (int c = 0; c < 4; c++) qfrag[c] = *(const bf16x8*)(qp + 32*c);
  }
  f32x4 oacc[8];
  #pragma unroll
  for (int dt = 0; dt < 8; dt++) oacc[dt] = (f32x4){0.f,0.f,0.f,0.f};
  float lrow = 0.f;

  const float LOG2E = 1.4426950408889634f;
  const float EOFF  = -11.541560327111707f;   // -8 * log2(e)

  stage(0, 0);

  for (int step = 0; step < nt; step++){
    if (step == ntA){
      // flush phase-A output
      float lt = lrow;
      lt += __shfl_xor(lt, 16);
      lt += __shfl_xor(lt, 32);
      float invl = 1.f / lt;
      size_t obase = ((size_t)(bI*2048 + qb + lc))*1024 + hb*128 + 4*lg;
      #pragma unroll
      for (int dt = 0; dt < 8; dt++){
        uint2 val;
        val.x = (unsigned)cvt_pk_bf16(oacc[dt][0]*invl, oacc[dt][1]*invl);
        val.y = (unsigned)cvt_pk_bf16(oacc[dt][2]*invl, oacc[dt][3]*invl);
        *(uint2*)&O2[obase + 16*dt] = val;
      }
      qb = iB*64 + w*16;
      const ushort_t* qp = Q2 + (mQ + qb + lc)*128 + 8*lg;
      #pragma unroll
      for (int c = 0; c < 4; c++) qfrag[c] = *(const bf16x8*)(qp + 32*c);
      #pragma unroll
      for (int dt = 0; dt < 8; dt++) oacc[dt] = (f32x4){0.f,0.f,0.f,0.f};
      lrow = 0.f;
    }
    int local = (step < ntA) ? step : step - ntA;
    bool isLast = (step == ntA - 1) || (step == nt - 1);
    int s0 = local * 64;
    int bsel = step & 1;

    if (step + 1 < nt){
      int nl = (step + 1 < ntA) ? step + 1 : step + 1 - ntA;
      stage(nl*64, bsel ^ 1);
      asm volatile("s_waitcnt vmcnt(8)\n\ts_barrier" ::: "memory");
    } else {
      asm volatile("s_waitcnt vmcnt(0)\n\ts_barrier" ::: "memory");
    }

    // ---- QK: S^T subtiles (rows = s-local, cols = q-local)
    f32x4 sacc[4];
    #pragma unroll
    for (int st = 0; st < 4; st++){
      f32x4 a2 = (f32x4){0.f,0.f,0.f,0.f};
      #pragma unroll
      for (int c = 0; c < 4; c++){
        bf16x8 kf = *(bf16x8*)&kbuf[bsel][(st*4 + c)*64 + l];
        a2 = __builtin_amdgcn_mfma_f32_16x16x32_bf16(kf, qfrag[c], a2, 0, 0, 0);
      }
      sacc[st] = a2;
    }
    if (isLast){
      int qg = qb + lc;
      #pragma unroll
      for (int st = 0; st < 4; st++)
        #pragma unroll
        for (int r = 0; r < 4; r++){
          int sg = s0 + st*16 + 4*lg + r;
          if (sg > qg) sacc[st][r] = -1e30f;
        }
    }

    // ---- p = exp(s - 8), lrow accumulated, cross-lane deferred
    float p_[4][4];
    #pragma unroll
    for (int st = 0; st < 4; st++)
      #pragma unroll
      for (int r = 0; r < 4; r++){
        float sv = fminf(fmaf(sacc[st][r], LOG2E, EOFF), 108.f);
        float pv = __builtin_amdgcn_exp2f(sv);
        p_[st][r] = pv;
        lrow += pv;
      }

    // ---- PV: O^T += V^T * P^T, two 32-s k-steps
    #pragma unroll
    for (int ks = 0; ks < 2; ks++){
      int pk0[2], pk1[2];
      #pragma unroll
      for (int pa = 0; pa < 2; pa++){
        pk0[pa] = cvt_pk_bf16(p_[2*ks][2*pa],   p_[2*ks][2*pa+1]);
        pk1[pa] = cvt_pk_bf16(p_[2*ks+1][2*pa], p_[2*ks+1][2*pa+1]);
      }
      union { int i[4]; bf16x8 v; } bfr;
      #pragma unroll
      for (int w2 = 0; w2 < 4; w2++){
        int v0 = __builtin_amdgcn_ds_bpermute(psel[w2], pk0[w2 & 1]);
        int v1 = __builtin_amdgcn_ds_bpermute(psel[w2], pk1[w2 & 1]);
        bfr.i[w2] = (lg >> 1) ? v1 : v0;
      }
      #pragma unroll
      for (int dt = 0; dt < 8; dt++){
        bf16x8 vf = *(bf16x8*)&vbuf[bsel][(dt*2 + ks)*64 + l];
        oacc[dt] = __builtin_amdgcn_mfma_f32_16x16x32_bf16(vf, bfr.v, oacc[dt], 0, 0, 0);
      }
    }
    asm volatile("s_barrier" ::: "memory");
  }

  // flush phase B
  float lt = lrow;
  lt += __shfl_xor(lt, 16);
  lt += __shfl_xor(lt, 32);
  float invl = 1.f / lt;
  size_t obase = ((size_t)(bI*2048 + qb + lc))*1024 + hb*128 + 4*lg;
  #pragma unroll
  for (int dt = 0; dt < 8; dt++){
    uint2 val;
    val.x = (unsigned)cvt_pk_bf16(oacc[dt][0]*invl, oacc[dt][1]*invl);
    val.y = (unsigned)cvt_pk_bf16(oacc[dt][2]*invl, oacc[dt][3]*invl);
    *(uint2*)&O2[obase + 16*dt] = val;
  }
}

// ---------------------------------------------------------------------------
// finalmm (MFMA): out[bt][j] = silu(bu[j] + sum_hd O2[bt][hd]*Wub[j][hd]).
// Tile 64(bt) x 128(j), K=1024 BK=32, 128 blocks.
// ---------------------------------------------------------------------------
__global__ __launch_bounds__(256) void finalmm(
    const ushort_t* __restrict__ O2,    // [8192][1024] bf16
    const ushort_t* __restrict__ Wub,   // [128][1024] bf16
    const float* __restrict__ bu,
    float* __restrict__ out)            // [8192][128]
{
  __shared__ ushort_t As[64*32]  __attribute__((aligned(16)));   // 4 KB
  __shared__ ushort_t Bs[128*32] __attribute__((aligned(16)));   // 8 KB
  int bt0 = blockIdx.x * 64;
  int tid = threadIdx.x;
  int w = tid >> 6, ln = tid & 63;
  int lc = ln & 15, lg = ln >> 4;
  int nj = w * 32;
  int srow = ln >> 2;
  int kseg = (ln & 3) * 8;

  f32x4 acc[4][2];
  #pragma unroll
  for (int si = 0; si < 4; si++)
    #pragma unroll
    for (int sj = 0; sj < 2; sj++) acc[si][sj] = (f32x4){0.f,0.f,0.f,0.f};

  const ushort_t* gA = O2  + (size_t)(bt0 + w*16 + srow)*1024 + kseg;
  const ushort_t* gB = Wub + (size_t)(w*32 + srow)*1024 + kseg;

  for (int kk = 0; kk < 32; kk++){
    int r0 = kk * 32;
    __syncthreads();
    async_cp16(&As[w*512],        gA + r0);
    async_cp16(&Bs[w*1024],       gB + r0);
    async_cp16(&Bs[w*1024 + 512], gB + r0 + 16*1024);
    __syncthreads();
    bf16x8 af[4], bfr[2];
    #pragma unroll
    for (int si = 0; si < 4; si++)
      af[si] = *(const bf16x8*)&As[(16*si + lc)*32 + 8*lg];
    #pragma unroll
    for (int sj = 0; sj < 2; sj++)
      bfr[sj] = *(const bf16x8*)&Bs[(nj + 16*sj + lc)*32 + 8*lg];
    #pragma unroll
    for (int si = 0; si < 4; si++)
      #pragma unroll
      for (int sj = 0; sj < 2; sj++)
        acc[si][sj] = __builtin_amdgcn_mfma_f32_16x16x32_bf16(af[si], bfr[sj],
                                                              acc[si][sj], 0,0,0);
  }

  float bv[2];
  #pragma unroll
  for (int sj = 0; sj < 2; sj++) bv[sj] = bu[nj + 16*sj + lc];
  #pragma unroll
  for (int si = 0; si < 4; si++)
    #pragma unroll
    for (int r = 0; r < 4; r++){
      int t = bt0 + 16*si + 4*lg + r;
      #pragma unroll
      for (int sj = 0; sj < 2; sj++)
        out[(size_t)t*128 + nj + 16*sj + lc] = silu_f(acc[si][sj][r] + bv[sj]);
    }
}

// ---------------------------------------------------------------------------
extern "C" void kernel_launch(void* const* d_in, const int* in_sizes, int n_in,
                              void* d_out, int out_size, void* d_ws, size_t ws_size,
                              hipStream_t stream) {
  const float* x  = (const float*)d_in[0];
  const float* Wq = (const float*)d_in[1];
  const float* bq = (const float*)d_in[2];
  const float* Wk = (const float*)d_in[3];
  const float* bk = (const float*)d_in[4];
  const float* Wv = (const float*)d_in[5];
  const float* Wu = (const float*)d_in[6];
  const float* bu = (const float*)d_in[7];
  float* out = (float*)d_out;

  // Workspace layout (generous slack; Xpad is 2,105,344 B — the round-7
  // failure was W2p overlapping Xpad's tail by 8 KB).
  char* ws = (char*)d_ws;
  ushort_t* Q2   = (ushort_t*)(ws + 0);            // 16 MB   [0, 16M)
  ushort_t* K2   = (ushort_t*)(ws + 16777216);     // 16 MB   [16M, 32M)
  ushort_t* V2t  = (ushort_t*)(ws + 33554432);     // 16 MB   [32M, 48M)
  ushort_t* O2   = (ushort_t*)(ws + 50331648);     // 16 MB   [48M, 64M)
  ushort_t* Xpad = (ushort_t*)(ws + 67108864);     // 2.008 MB [64M, ..)
  ushort_t* W2p  = (ushort_t*)(ws + 70254592);     // 2.5 MB  (64M + 3M)
  ushort_t* Wvp  = (ushort_t*)(ws + 73400320);     // 0.25 MB (64M + 6M)
  ushort_t* Wub  = (ushort_t*)(ws + 74448896);     // 0.25 MB (64M + 7M)

  wprep<<<dim3(3200, 1, 1), 256, 0, stream>>>(Wq, Wk, Wv, Wu, W2p, Wvp, Wub);
  xprep<<<dim3(1028, 4, 1), 256, 0, stream>>>(x, Xpad);

  gemm_qk<<<dim3(16, 64, 1), 256, 0, stream>>>(Xpad, W2p, bq, bk, Q2, K2);
  gemm_v<<<dim3(8, 64, 1), 256, 0, stream>>>(Xpad, Wvp, V2t);

  attn<<<dim3(512, 1, 1), 256, 0, stream>>>(Q2, K2, V2t, O2);
  finalmm<<<dim3(128, 1, 1), 256, 0, stream>>>(O2, Wub, bu, out);
}

// Round 10
// 213.147 us; speedup vs baseline: 1.4198x; 1.0134x over previous
//
#include <hip/hip_runtime.h>
#include <hip/hip_bf16.h>
#include <stdint.h>

// B=4, T=2048, K(=D)=128, H=8, KS=5, DIL=2, PAD=8, M=B*H=32
// scale = 128^0.25 ; inv = 0.29730177875068026

typedef __attribute__((ext_vector_type(8))) short bf16x8;
typedef __attribute__((ext_vector_type(4))) float f32x4;
typedef __attribute__((ext_vector_type(4))) int   i32x4;
typedef unsigned short ushort_t;

__device__ __forceinline__ unsigned short f2bf(float x){
  union{float f; unsigned u;} v; v.f = x;
  unsigned r = v.u + 0x7FFFu + ((v.u >> 16) & 1u);   // RNE
  return (unsigned short)(r >> 16);
}
__device__ __forceinline__ float silu_f(float x){ return x / (1.f + __expf(-x)); }

__device__ __forceinline__ int cvt_pk_bf16(float lo, float hi){
  int r;
  asm("v_cvt_pk_bf16_f32 %0, %1, %2" : "=v"(r) : "v"(lo), "v"(hi));
  return r;
}

__device__ __forceinline__ void async_cp16(void* lds, const void* g){
  __builtin_amdgcn_global_load_lds(
      (const __attribute__((address_space(1))) unsigned int*)g,
      (__attribute__((address_space(3))) unsigned int*)lds, 16, 0, 0);
}

// ---------------------------------------------------------------------------
// Weight prep. K-dim order for the qk GEMM is r' = j*128 + ci.
// ---------------------------------------------------------------------------
__global__ __launch_bounds__(256) void wprep(const float* __restrict__ Wq,
                                             const float* __restrict__ Wk,
                                             const float* __restrict__ Wv,
                                             const float* __restrict__ Wu,
                                             ushort_t* __restrict__ W2p,
                                             ushort_t* __restrict__ Wvp,
                                             ushort_t* __restrict__ Wub){
  int n = blockIdx.x;
  int tid = threadIdx.x;
  if (n < 2048){
    int qk = n >> 10, h = (n >> 7) & 7, d = n & 127;
    const float* src = (qk ? Wk : Wq) + (size_t)(d*8 + h)*640;
    for (int rp = tid; rp < 640; rp += 256){
      int j = rp >> 7, ci = rp & 127;
      W2p[(size_t)n*640 + rp] = f2bf(src[ci*5 + j]);
    }
  } else if (n < 3072){
    int co = n - 2048;
    for (int r = tid; r < 128; r += 256)
      Wvp[(size_t)co*128 + r] = f2bf(Wv[(size_t)co*128 + r]);
  } else {
    int j = n - 3072;
    for (int r = tid; r < 1024; r += 256)
      Wub[(size_t)j*1024 + r] = f2bf(Wu[(size_t)j*1024 + r]);
  }
}

// ---------------------------------------------------------------------------
// xprep: Xpad[b][rt][ci] = (rt < 8) ? 0 : bf16(x[b][rt-8][ci]).  [4][2056][128]
// ---------------------------------------------------------------------------
__global__ __launch_bounds__(256) void xprep(const float* __restrict__ x,
                                             ushort_t* __restrict__ Xpad){
  int b  = blockIdx.y;
  int rt = blockIdx.x * 2 + (threadIdx.x >> 7);
  int ci = threadIdx.x & 127;
  int t  = rt - 8;
  ushort_t v = 0;
  if (t >= 0) v = f2bf(x[((size_t)(b*2048 + t))*128 + ci]);
  Xpad[((size_t)(b*2056 + rt))*128 + ci] = v;
}

// ---------------------------------------------------------------------------
// gemm_qk: C^T[t][n] = sum_{j,ci} Xpad[b][tl+2j][ci] * W2p[n][j*128+ci],
// K=640, tile 128x128 BK=32, DOUBLE-BUFFERED (vmcnt(4) + raw s_barrier).
// ---------------------------------------------------------------------------
__global__ __launch_bounds__(256) void gemm_qk(
    const ushort_t* __restrict__ Xpad,  // [4][2056][128]
    const ushort_t* __restrict__ W2p,   // [2048][640]
    const float* __restrict__ bq, const float* __restrict__ bk,
    ushort_t* __restrict__ Q2, ushort_t* __restrict__ K2)
{
  __shared__ ushort_t As[2][128*32] __attribute__((aligned(16)));
  __shared__ ushort_t Bs[2][128*32] __attribute__((aligned(16)));
  int n0  = blockIdx.x * 128;
  int bt0 = blockIdx.y * 128;
  int tid = threadIdx.x;
  int w = tid >> 6, ln = tid & 63;
  int lc = ln & 15, lg = ln >> 4;
  int mi = (w & 1) * 64, nj = (w >> 1) * 64;

  int srow = ln >> 2;
  int kseg = (ln & 3) * 8;

  f32x4 acc[4][4];
  #pragma unroll
  for (int si = 0; si < 4; si++)
    #pragma unroll
    for (int sj = 0; sj < 4; sj++) acc[si][sj] = (f32x4){0.f,0.f,0.f,0.f};

  int b = bt0 >> 11, tl0 = bt0 & 2047;
  const ushort_t* gA = Xpad + (size_t)(b*2056 + tl0 + w*32 + srow)*128 + kseg;
  const ushort_t* gB = W2p + (size_t)(n0  + w*32 + srow)*640 + kseg;

  auto stageAB = [&](int kk, int bsel){
    int j = kk >> 2, ci0 = (kk & 3) * 32;
    int r0 = kk * 32;
    const ushort_t* a0 = gA + (size_t)(2*j)*128 + ci0;
    async_cp16(&As[bsel][w*1024],       a0);
    async_cp16(&As[bsel][w*1024 + 512], a0 + 16*128);
    async_cp16(&Bs[bsel][w*1024],       gB + r0);
    async_cp16(&Bs[bsel][w*1024 + 512], gB + r0 + 16*640);
  };

  stageAB(0, 0);
  for (int kk = 0; kk < 20; kk++){
    int bsel = kk & 1;
    if (kk + 1 < 20){
      stageAB(kk + 1, bsel ^ 1);
      asm volatile("s_waitcnt vmcnt(4)\n\ts_barrier" ::: "memory");
    } else {
      asm volatile("s_waitcnt vmcnt(0)\n\ts_barrier" ::: "memory");
    }
    bf16x8 af[4], bfr[4];
    #pragma unroll
    for (int si = 0; si < 4; si++)
      af[si] = *(const bf16x8*)&As[bsel][(mi + 16*si + lc)*32 + 8*lg];
    #pragma unroll
    for (int sj = 0; sj < 4; sj++)
      bfr[sj] = *(const bf16x8*)&Bs[bsel][(nj + 16*sj + lc)*32 + 8*lg];
    #pragma unroll
    for (int si = 0; si < 4; si++)
      #pragma unroll
      for (int sj = 0; sj < 4; sj++)
        acc[si][sj] = __builtin_amdgcn_mfma_f32_16x16x32_bf16(af[si], bfr[sj],
                                                              acc[si][sj], 0,0,0);
    asm volatile("s_barrier" ::: "memory");
  }

  const float inv_scale = 0.29730177875068026f;
  int qk = n0 >> 10, h = (n0 >> 7) & 7;
  const float* bias = qk ? bk : bq;
  ushort_t* dst = qk ? K2 : Q2;
  float bv[4];
  #pragma unroll
  for (int sj = 0; sj < 4; sj++) bv[sj] = bias[(nj + 16*sj + lc)*8 + h];

  #pragma unroll
  for (int si = 0; si < 4; si++){
    int btb = bt0 + mi + 16*si + 4*lg;
    #pragma unroll
    for (int r = 0; r < 4; r++){
      int t = btb + r;
      int bb = t >> 11, tl = t & 2047;
      size_t rowoff = ((size_t)(bb*8 + (tl >> 8))*2048 + (tl & 255)*8 + h)*128;
      #pragma unroll
      for (int sj = 0; sj < 4; sj++){
        int d = nj + 16*sj + lc;
        dst[rowoff + d] = f2bf(silu_f(acc[si][sj][r] + bv[sj]) * inv_scale);
      }
    }
  }
}

// ---------------------------------------------------------------------------
// gemm_v: C^T[t][co] = sum_ci Xpad[b][tl+8][ci] * Wvp[co][ci], K=128.
// ---------------------------------------------------------------------------
__global__ __launch_bounds__(256) void gemm_v(
    const ushort_t* __restrict__ Xpad,  // [4][2056][128]
    const ushort_t* __restrict__ Wvp,   // [1024][128]
    ushort_t* __restrict__ V2t)
{
  __shared__ ushort_t As[128*32] __attribute__((aligned(16)));
  __shared__ ushort_t Bs[128*32] __attribute__((aligned(16)));
  int n0  = blockIdx.x * 128;
  int bt0 = blockIdx.y * 128;
  int tid = threadIdx.x;
  int w = tid >> 6, ln = tid & 63;
  int lc = ln & 15, lg = ln >> 4;
  int mi = (w & 1) * 64, nj = (w >> 1) * 64;
  int srow = ln >> 2;
  int kseg = (ln & 3) * 8;

  f32x4 acc[4][4];
  #pragma unroll
  for (int si = 0; si < 4; si++)
    #pragma unroll
    for (int sj = 0; sj < 4; sj++) acc[si][sj] = (f32x4){0.f,0.f,0.f,0.f};

  int b = bt0 >> 11, tl0 = bt0 & 2047;
  const ushort_t* gA = Xpad + (size_t)(b*2056 + 8 + tl0 + w*32 + srow)*128 + kseg;
  const ushort_t* gB = Wvp  + (size_t)(n0 + w*32 + srow)*128 + kseg;

  for (int kk = 0; kk < 4; kk++){
    int r0 = kk * 32;
    __syncthreads();
    async_cp16(&As[w*1024],        gA + r0);
    async_cp16(&As[w*1024 + 512],  gA + r0 + 16*128);
    async_cp16(&Bs[w*1024],        gB + r0);
    async_cp16(&Bs[w*1024 + 512],  gB + r0 + 16*128);
    __syncthreads();
    bf16x8 af[4], bfr[4];
    #pragma unroll
    for (int si = 0; si < 4; si++)
      af[si] = *(const bf16x8*)&As[(mi + 16*si + lc)*32 + 8*lg];
    #pragma unroll
    for (int sj = 0; sj < 4; sj++)
      bfr[sj] = *(const bf16x8*)&Bs[(nj + 16*sj + lc)*32 + 8*lg];
    #pragma unroll
    for (int si = 0; si < 4; si++)
      #pragma unroll
      for (int sj = 0; sj < 4; sj++)
        acc[si][sj] = __builtin_amdgcn_mfma_f32_16x16x32_bf16(af[si], bfr[sj],
                                                              acc[si][sj], 0,0,0);
  }

  #pragma unroll
  for (int si = 0; si < 4; si++){
    int btb = bt0 + mi + 16*si + 4*lg;
    #pragma unroll
    for (int r = 0; r < 4; r++){
      int t = btb + r;
      int bb = t >> 11, tl = t & 2047;
      int mm = bb*8 + (tl >> 8);
      int tpb = (tl & 255)*8;
      #pragma unroll
      for (int sj = 0; sj < 4; sj++){
        int co = n0 + nj + 16*sj + lc;
        int d = co >> 3, hh = co & 7;
        V2t[((size_t)mm*128 + d)*2048 + tpb + hh] = f2bf(silu_f(acc[si][sj][r]));
      }
    }
  }
}

// ---------------------------------------------------------------------------
// Flash attention — EXACT round-8 kernel (benched 80.8us, passed). 256-thr
// blocks (4 waves x 16 q), paired causal blocks (i,31-i) -> uniform 33
// tile-units; 64-s tiles; dbuf global_load_lds staging w/ vmcnt(8); no
// online max (bounded inputs; exp(s-8)); bf16 O2 epilogue.
// ---------------------------------------------------------------------------
__global__ __launch_bounds__(256) void attn(
    const ushort_t* __restrict__ Q2,   // [32][2048][128]
    const ushort_t* __restrict__ K2,   // [32][2048][128]
    const ushort_t* __restrict__ V2t,  // [32][128][2048]
    ushort_t* __restrict__ O2)         // [8192][1024] bf16
{
  __shared__ i32x4 kbuf[2][1024];      // [buf][(st*4+c)*64 + lane]  16KB each
  __shared__ i32x4 vbuf[2][1024];      // [buf][(dt*2+ks)*64 + lane] 16KB each

  int bid = blockIdx.x;                      // 512 blocks
  int m   = ((bid & 7) << 2) | ((bid >> 3) & 3);  // XCD-L2 locality swizzle
  int ip  = bid >> 5;                        // pair index 0..15
  int tid = threadIdx.x;
  int w = tid >> 6, l = tid & 63;
  int lc = l & 15, lg = l >> 4;

  int iA = 31 - ip, iB = ip;
  int ntA = iA + 1;
  const int nt = 33;

  const size_t mQ = (size_t)m * 2048;
  const ushort_t* Kbase = K2  + mQ * 128;
  const ushort_t* Vbase = V2t + (size_t)m * 128 * 2048;
  int hb = m & 7, bI = m >> 3;

  int psel[4];
  #pragma unroll
  for (int w2 = 0; w2 < 4; w2++)
    psel[w2] = ((((2*(lg & 1) + (w2 >> 1)) << 4) | lc) << 2);

  auto stage = [&](int s0, int bsel){
    const ushort_t* krow = Kbase + (size_t)(s0 + w*16 + lc)*128 + 8*lg;
    #pragma unroll
    for (int c = 0; c < 4; c++)
      async_cp16(&kbuf[bsel][(w*4 + c)*64], krow + 32*c);
    #pragma unroll
    for (int j = 0; j < 4; j++){
      int dt = w*2 + (j >> 1);
      const ushort_t* vrow = Vbase + (size_t)(dt*16 + lc)*2048
                             + s0 + (j & 1)*32 + 8*lg;
      async_cp16(&vbuf[bsel][(w*4 + j)*64], vrow);
    }
  };

  int qb = iA*64 + w*16;
  bf16x8 qfrag[4];
  {
    const ushort_t* qp = Q2 + (mQ + qb + lc)*128 + 8*lg;
    #pragma unroll
    for (int c = 0; c < 4; c++) qfrag[c] = *(const bf16x8*)(qp + 32*c);
  }
  f32x4 oacc[8];
  #pragma unroll
  for (int dt = 0; dt < 8; dt++) oacc[dt] = (f32x4){0.f,0.f,0.f,0.f};
  float lrow = 0.f;

  const float LOG2E = 1.4426950408889634f;
  const float EOFF  = -11.541560327111707f;   // -8 * log2(e)

  stage(0, 0);

  for (int step = 0; step < nt; step++){
    if (step == ntA){
      // flush phase-A output
      float lt = lrow;
      lt += __shfl_xor(lt, 16);
      lt += __shfl_xor(lt, 32);
      float invl = 1.f / lt;
      size_t obase = ((size_t)(bI*2048 + qb + lc))*1024 + hb*128 + 4*lg;
      #pragma unroll
      for (int dt = 0; dt < 8; dt++){
        uint2 val;
        val.x = (unsigned)cvt_pk_bf16(oacc[dt][0]*invl, oacc[dt][1]*invl);
        val.y = (unsigned)cvt_pk_bf16(oacc[dt][2]*invl, oacc[dt][3]*invl);
        *(uint2*)&O2[obase + 16*dt] = val;
      }
      qb = iB*64 + w*16;
      const ushort_t* qp = Q2 + (mQ + qb + lc)*128 + 8*lg;
      #pragma unroll
      for (int c = 0; c < 4; c++) qfrag[c] = *(const bf16x8*)(qp + 32*c);
      #pragma unroll
      for (int dt = 0; dt < 8; dt++) oacc[dt] = (f32x4){0.f,0.f,0.f,0.f};
      lrow = 0.f;
    }
    int local = (step < ntA) ? step : step - ntA;
    bool isLast = (step == ntA - 1) || (step == nt - 1);
    int s0 = local * 64;
    int bsel = step & 1;

    if (step + 1 < nt){
      int nl = (step + 1 < ntA) ? step + 1 : step + 1 - ntA;
      stage(nl*64, bsel ^ 1);
      asm volatile("s_waitcnt vmcnt(8)\n\ts_barrier" ::: "memory");
    } else {
      asm volatile("s_waitcnt vmcnt(0)\n\ts_barrier" ::: "memory");
    }

    // ---- QK: S^T subtiles (rows = s-local, cols = q-local)
    f32x4 sacc[4];
    #pragma unroll
    for (int st = 0; st < 4; st++){
      f32x4 a2 = (f32x4){0.f,0.f,0.f,0.f};
      #pragma unroll
      for (int c = 0; c < 4; c++){
        bf16x8 kf = *(bf16x8*)&kbuf[bsel][(st*4 + c)*64 + l];
        a2 = __builtin_amdgcn_mfma_f32_16x16x32_bf16(kf, qfrag[c], a2, 0, 0, 0);
      }
      sacc[st] = a2;
    }
    if (isLast){
      int qg = qb + lc;
      #pragma unroll
      for (int st = 0; st < 4; st++)
        #pragma unroll
        for (int r = 0; r < 4; r++){
          int sg = s0 + st*16 + 4*lg + r;
          if (sg > qg) sacc[st][r] = -1e30f;
        }
    }

    // ---- p = exp(s - 8), lrow accumulated, cross-lane deferred
    float p_[4][4];
    #pragma unroll
    for (int st = 0; st < 4; st++)
      #pragma unroll
      for (int r = 0; r < 4; r++){
        float sv = fminf(fmaf(sacc[st][r], LOG2E, EOFF), 108.f);
        float pv = __builtin_amdgcn_exp2f(sv);
        p_[st][r] = pv;
        lrow += pv;
      }

    // ---- PV: O^T += V^T * P^T, two 32-s k-steps
    #pragma unroll
    for (int ks = 0; ks < 2; ks++){
      int pk0[2], pk1[2];
      #pragma unroll
      for (int pa = 0; pa < 2; pa++){
        pk0[pa] = cvt_pk_bf16(p_[2*ks][2*pa],   p_[2*ks][2*pa+1]);
        pk1[pa] = cvt_pk_bf16(p_[2*ks+1][2*pa], p_[2*ks+1][2*pa+1]);
      }
      union { int i[4]; bf16x8 v; } bfr;
      #pragma unroll
      for (int w2 = 0; w2 < 4; w2++){
        int v0 = __builtin_amdgcn_ds_bpermute(psel[w2], pk0[w2 & 1]);
        int v1 = __builtin_amdgcn_ds_bpermute(psel[w2], pk1[w2 & 1]);
        bfr.i[w2] = (lg >> 1) ? v1 : v0;
      }
      #pragma unroll
      for (int dt = 0; dt < 8; dt++){
        bf16x8 vf = *(bf16x8*)&vbuf[bsel][(dt*2 + ks)*64 + l];
        oacc[dt] = __builtin_amdgcn_mfma_f32_16x16x32_bf16(vf, bfr.v, oacc[dt], 0, 0, 0);
      }
    }
    asm volatile("s_barrier" ::: "memory");
  }

  // flush phase B
  float lt = lrow;
  lt += __shfl_xor(lt, 16);
  lt += __shfl_xor(lt, 32);
  float invl = 1.f / lt;
  size_t obase = ((size_t)(bI*2048 + qb + lc))*1024 + hb*128 + 4*lg;
  #pragma unroll
  for (int dt = 0; dt < 8; dt++){
    uint2 val;
    val.x = (unsigned)cvt_pk_bf16(oacc[dt][0]*invl, oacc[dt][1]*invl);
    val.y = (unsigned)cvt_pk_bf16(oacc[dt][2]*invl, oacc[dt][3]*invl);
    *(uint2*)&O2[obase + 16*dt] = val;
  }
}

// ---------------------------------------------------------------------------
// finalmm (MFMA): out[bt][j] = silu(bu[j] + sum_hd O2[bt][hd]*Wub[j][hd]).
// Tile 32(bt) x 128(j), K=1024 BK=32, 256 blocks (full CU coverage).
// ---------------------------------------------------------------------------
__global__ __launch_bounds__(256) void finalmm(
    const ushort_t* __restrict__ O2,    // [8192][1024] bf16
    const ushort_t* __restrict__ Wub,   // [128][1024] bf16
    const float* __restrict__ bu,
    float* __restrict__ out)            // [8192][128]
{
  __shared__ ushort_t As[32*32]  __attribute__((aligned(16)));   // 2 KB
  __shared__ ushort_t Bs[128*32] __attribute__((aligned(16)));   // 8 KB
  int bt0 = blockIdx.x * 32;
  int tid = threadIdx.x;
  int w = tid >> 6, ln = tid & 63;
  int lc = ln & 15, lg = ln >> 4;
  int nj = w * 32;
  int srow = ln >> 2;
  int kseg = (ln & 3) * 8;

  f32x4 acc[2][2];
  #pragma unroll
  for (int si = 0; si < 2; si++)
    #pragma unroll
    for (int sj = 0; sj < 2; sj++) acc[si][sj] = (f32x4){0.f,0.f,0.f,0.f};

  const ushort_t* gA = O2  + (size_t)(bt0 + (w & 1)*16 + srow)*1024 + kseg;
  const ushort_t* gB = Wub + (size_t)(w*32 + srow)*1024 + kseg;

  for (int kk = 0; kk < 32; kk++){
    int r0 = kk * 32;
    __syncthreads();
    if (w < 2) async_cp16(&As[w*512], gA + r0);
    async_cp16(&Bs[w*1024],       gB + r0);
    async_cp16(&Bs[w*1024 + 512], gB + r0 + 16*1024);
    __syncthreads();
    bf16x8 af[2], bfr[2];
    #pragma unroll
    for (int si = 0; si < 2; si++)
      af[si] = *(const bf16x8*)&As[(16*si + lc)*32 + 8*lg];
    #pragma unroll
    for (int sj = 0; sj < 2; sj++)
      bfr[sj] = *(const bf16x8*)&Bs[(nj + 16*sj + lc)*32 + 8*lg];
    #pragma unroll
    for (int si = 0; si < 2; si++)
      #pragma unroll
      for (int sj = 0; sj < 2; sj++)
        acc[si][sj] = __builtin_amdgcn_mfma_f32_16x16x32_bf16(af[si], bfr[sj],
                                                              acc[si][sj], 0,0,0);
  }

  float bv[2];
  #pragma unroll
  for (int sj = 0; sj < 2; sj++) bv[sj] = bu[nj + 16*sj + lc];
  #pragma unroll
  for (int si = 0; si < 2; si++)
    #pragma unroll
    for (int r = 0; r < 4; r++){
      int t = bt0 + 16*si + 4*lg + r;
      #pragma unroll
      for (int sj = 0; sj < 2; sj++)
        out[(size_t)t*128 + nj + 16*sj + lc] = silu_f(acc[si][sj][r] + bv[sj]);
    }
}

// ---------------------------------------------------------------------------
extern "C" void kernel_launch(void* const* d_in, const int* in_sizes, int n_in,
                              void* d_out, int out_size, void* d_ws, size_t ws_size,
                              hipStream_t stream) {
  const float* x  = (const float*)d_in[0];
  const float* Wq = (const float*)d_in[1];
  const float* bq = (const float*)d_in[2];
  const float* Wk = (const float*)d_in[3];
  const float* bk = (const float*)d_in[4];
  const float* Wv = (const float*)d_in[5];
  const float* Wu = (const float*)d_in[6];
  const float* bu = (const float*)d_in[7];
  float* out = (float*)d_out;

  // Workspace layout (generous slack; Xpad is 2,105,344 B)
  char* ws = (char*)d_ws;
  ushort_t* Q2   = (ushort_t*)(ws + 0);            // 16 MB
  ushort_t* K2   = (ushort_t*)(ws + 16777216);     // 16 MB
  ushort_t* V2t  = (ushort_t*)(ws + 33554432);     // 16 MB
  ushort_t* O2   = (ushort_t*)(ws + 50331648);     // 16 MB (bf16 [8192][1024])
  ushort_t* Xpad = (ushort_t*)(ws + 67108864);     // 2.008 MB
  ushort_t* W2p  = (ushort_t*)(ws + 70254592);     // 2.5 MB
  ushort_t* Wvp  = (ushort_t*)(ws + 73400320);     // 0.25 MB
  ushort_t* Wub  = (ushort_t*)(ws + 74448896);     // 0.25 MB

  wprep<<<dim3(3200, 1, 1), 256, 0, stream>>>(Wq, Wk, Wv, Wu, W2p, Wvp, Wub);
  xprep<<<dim3(1028, 4, 1), 256, 0, stream>>>(x, Xpad);

  gemm_qk<<<dim3(16, 64, 1), 256, 0, stream>>>(Xpad, W2p, bq, bk, Q2, K2);
  gemm_v<<<dim3(8, 64, 1), 256, 0, stream>>>(Xpad, Wvp, V2t);

  attn<<<dim3(512, 1, 1), 256, 0, stream>>>(Q2, K2, V2t, O2);
  finalmm<<<dim3(256, 1, 1), 256, 0, stream>>>(O2, Wub, bu, out);
}

// Round 13
// 206.523 us; speedup vs baseline: 1.4653x; 1.0321x over previous
//
#include <hip/hip_runtime.h>
#include <hip/hip_bf16.h>
#include <stdint.h>

// B=4, T=2048, K(=D)=128, H=8, KS=5, DIL=2, PAD=8, M=B*H=32
// scale = 128^0.25 ; inv = 0.29730177875068026

typedef __attribute__((ext_vector_type(8))) short bf16x8;
typedef __attribute__((ext_vector_type(4))) float f32x4;
typedef __attribute__((ext_vector_type(4))) int   i32x4;
typedef unsigned short ushort_t;

__device__ __forceinline__ unsigned short f2bf(float x){
  union{float f; unsigned u;} v; v.f = x;
  unsigned r = v.u + 0x7FFFu + ((v.u >> 16) & 1u);   // RNE
  return (unsigned short)(r >> 16);
}
__device__ __forceinline__ float silu_f(float x){ return x / (1.f + __expf(-x)); }

__device__ __forceinline__ int cvt_pk_bf16(float lo, float hi){
  int r;
  asm("v_cvt_pk_bf16_f32 %0, %1, %2" : "=v"(r) : "v"(lo), "v"(hi));
  return r;
}

__device__ __forceinline__ void async_cp16(void* lds, const void* g){
  __builtin_amdgcn_global_load_lds(
      (const __attribute__((address_space(1))) unsigned int*)g,
      (__attribute__((address_space(3))) unsigned int*)lds, 16, 0, 0);
}

// ---------------------------------------------------------------------------
// prep = wprep + xprep merged (one dispatch). Bodies identical to round-10's
// separate kernels (audited equivalent).
//   n <  2048:        W2p[(qk*8+h)*128+d][j*128+ci] = bf16(W{q,k}[d*8+h][ci*5+j])
//   n in [2048,3072): Wvp[co][ci] = bf16(Wv[co][ci])
//   n in [3072,3200): Wub[j][hd]  = bf16(Wu[j][hd])
//   n in [3200,7312): Xpad[b][rt][ci] = (rt<8) ? 0 : bf16(x[b][rt-8][ci])
// ---------------------------------------------------------------------------
__global__ __launch_bounds__(256) void prep(const float* __restrict__ Wq,
                                            const float* __restrict__ Wk,
                                            const float* __restrict__ Wv,
                                            const float* __restrict__ Wu,
                                            const float* __restrict__ x,
                                            ushort_t* __restrict__ W2p,
                                            ushort_t* __restrict__ Wvp,
                                            ushort_t* __restrict__ Wub,
                                            ushort_t* __restrict__ Xpad){
  int n = blockIdx.x;
  int tid = threadIdx.x;
  if (n < 2048){
    int qk = n >> 10, h = (n >> 7) & 7, d = n & 127;
    const float* src = (qk ? Wk : Wq) + (size_t)(d*8 + h)*640;
    for (int rp = tid; rp < 640; rp += 256){
      int j = rp >> 7, ci = rp & 127;
      W2p[(size_t)n*640 + rp] = f2bf(src[ci*5 + j]);
    }
  } else if (n < 3072){
    int co = n - 2048;
    for (int r = tid; r < 128; r += 256)
      Wvp[(size_t)co*128 + r] = f2bf(Wv[(size_t)co*128 + r]);
  } else if (n < 3200){
    int j = n - 3072;
    for (int r = tid; r < 1024; r += 256)
      Wub[(size_t)j*1024 + r] = f2bf(Wu[(size_t)j*1024 + r]);
  } else {
    int idx = n - 3200;              // 0..4111
    int b   = idx & 3;
    int rt  = (idx >> 2) * 2 + (tid >> 7);
    int ci  = tid & 127;
    int t   = rt - 8;
    ushort_t v = 0;
    if (t >= 0) v = f2bf(x[((size_t)(b*2048 + t))*128 + ci]);
    Xpad[((size_t)(b*2056 + rt))*128 + ci] = v;
  }
}

// ---------------------------------------------------------------------------
// gemm_qkv: merged dispatch. blockIdx.x < 16 -> qk path (K=640, dbuf,
// round-10 gemm_qk verbatim). blockIdx.x >= 16 -> v path (K=128,
// round-10 gemm_v verbatim, using buffer slot 0).
// ---------------------------------------------------------------------------
__global__ __launch_bounds__(256) void gemm_qkv(
    const ushort_t* __restrict__ Xpad,  // [4][2056][128]
    const ushort_t* __restrict__ W2p,   // [2048][640]
    const ushort_t* __restrict__ Wvp,   // [1024][128]
    const float* __restrict__ bq, const float* __restrict__ bk,
    ushort_t* __restrict__ Q2, ushort_t* __restrict__ K2,
    ushort_t* __restrict__ V2t)
{
  __shared__ ushort_t As[2][128*32] __attribute__((aligned(16)));
  __shared__ ushort_t Bs[2][128*32] __attribute__((aligned(16)));
  int bt0 = blockIdx.y * 128;
  int tid = threadIdx.x;
  int w = tid >> 6, ln = tid & 63;
  int lc = ln & 15, lg = ln >> 4;
  int mi = (w & 1) * 64, nj = (w >> 1) * 64;
  int srow = ln >> 2;
  int kseg = (ln & 3) * 8;
  int b = bt0 >> 11, tl0 = bt0 & 2047;

  f32x4 acc[4][4];
  #pragma unroll
  for (int si = 0; si < 4; si++)
    #pragma unroll
    for (int sj = 0; sj < 4; sj++) acc[si][sj] = (f32x4){0.f,0.f,0.f,0.f};

  if (blockIdx.x < 16){
    // ---------------- qk path (round-10 gemm_qk verbatim) ----------------
    int n0 = blockIdx.x * 128;
    const ushort_t* gA = Xpad + (size_t)(b*2056 + tl0 + w*32 + srow)*128 + kseg;
    const ushort_t* gB = W2p + (size_t)(n0  + w*32 + srow)*640 + kseg;

    auto stageAB = [&](int kk, int bsel){
      int j = kk >> 2, ci0 = (kk & 3) * 32;
      int r0 = kk * 32;
      const ushort_t* a0 = gA + (size_t)(2*j)*128 + ci0;
      async_cp16(&As[bsel][w*1024],       a0);
      async_cp16(&As[bsel][w*1024 + 512], a0 + 16*128);
      async_cp16(&Bs[bsel][w*1024],       gB + r0);
      async_cp16(&Bs[bsel][w*1024 + 512], gB + r0 + 16*640);
    };

    stageAB(0, 0);
    for (int kk = 0; kk < 20; kk++){
      int bsel = kk & 1;
      if (kk + 1 < 20){
        stageAB(kk + 1, bsel ^ 1);
        asm volatile("s_waitcnt vmcnt(4)\n\ts_barrier" ::: "memory");
      } else {
        asm volatile("s_waitcnt vmcnt(0)\n\ts_barrier" ::: "memory");
      }
      bf16x8 af[4], bfr[4];
      #pragma unroll
      for (int si = 0; si < 4; si++)
        af[si] = *(const bf16x8*)&As[bsel][(mi + 16*si + lc)*32 + 8*lg];
      #pragma unroll
      for (int sj = 0; sj < 4; sj++)
        bfr[sj] = *(const bf16x8*)&Bs[bsel][(nj + 16*sj + lc)*32 + 8*lg];
      #pragma unroll
      for (int si = 0; si < 4; si++)
        #pragma unroll
        for (int sj = 0; sj < 4; sj++)
          acc[si][sj] = __builtin_amdgcn_mfma_f32_16x16x32_bf16(af[si], bfr[sj],
                                                                acc[si][sj], 0,0,0);
      asm volatile("s_barrier" ::: "memory");
    }

    const float inv_scale = 0.29730177875068026f;
    int qk = n0 >> 10, h = (n0 >> 7) & 7;
    const float* bias = qk ? bk : bq;
    ushort_t* dst = qk ? K2 : Q2;
    float bv[4];
    #pragma unroll
    for (int sj = 0; sj < 4; sj++) bv[sj] = bias[(nj + 16*sj + lc)*8 + h];

    #pragma unroll
    for (int si = 0; si < 4; si++){
      int btb = bt0 + mi + 16*si + 4*lg;
      #pragma unroll
      for (int r = 0; r < 4; r++){
        int t = btb + r;
        int bb = t >> 11, tl = t & 2047;
        size_t rowoff = ((size_t)(bb*8 + (tl >> 8))*2048 + (tl & 255)*8 + h)*128;
        #pragma unroll
        for (int sj = 0; sj < 4; sj++){
          int d = nj + 16*sj + lc;
          dst[rowoff + d] = f2bf(silu_f(acc[si][sj][r] + bv[sj]) * inv_scale);
        }
      }
    }
  } else {
    // ---------------- v path (round-10 gemm_v verbatim, slot 0) ----------
    int n0 = (blockIdx.x - 16) * 128;
    const ushort_t* gA = Xpad + (size_t)(b*2056 + 8 + tl0 + w*32 + srow)*128 + kseg;
    const ushort_t* gB = Wvp  + (size_t)(n0 + w*32 + srow)*128 + kseg;

    for (int kk = 0; kk < 4; kk++){
      int r0 = kk * 32;
      __syncthreads();
      async_cp16(&As[0][w*1024],        gA + r0);
      async_cp16(&As[0][w*1024 + 512],  gA + r0 + 16*128);
      async_cp16(&Bs[0][w*1024],        gB + r0);
      async_cp16(&Bs[0][w*1024 + 512],  gB + r0 + 16*128);
      __syncthreads();
      bf16x8 af[4], bfr[4];
      #pragma unroll
      for (int si = 0; si < 4; si++)
        af[si] = *(const bf16x8*)&As[0][(mi + 16*si + lc)*32 + 8*lg];
      #pragma unroll
      for (int sj = 0; sj < 4; sj++)
        bfr[sj] = *(const bf16x8*)&Bs[0][(nj + 16*sj + lc)*32 + 8*lg];
      #pragma unroll
      for (int si = 0; si < 4; si++)
        #pragma unroll
        for (int sj = 0; sj < 4; sj++)
          acc[si][sj] = __builtin_amdgcn_mfma_f32_16x16x32_bf16(af[si], bfr[sj],
                                                                acc[si][sj], 0,0,0);
    }

    #pragma unroll
    for (int si = 0; si < 4; si++){
      int btb = bt0 + mi + 16*si + 4*lg;
      #pragma unroll
      for (int r = 0; r < 4; r++){
        int t = btb + r;
        int bb = t >> 11, tl = t & 2047;
        int mm = bb*8 + (tl >> 8);
        int tpb = (tl & 255)*8;
        #pragma unroll
        for (int sj = 0; sj < 4; sj++){
          int co = n0 + nj + 16*sj + lc;
          int d = co >> 3, hh = co & 7;
          V2t[((size_t)mm*128 + d)*2048 + tpb + hh] = f2bf(silu_f(acc[si][sj][r]));
        }
      }
    }
  }
}

// ---------------------------------------------------------------------------
// Flash attention — EXACT round-8/round-10 kernel (passed twice). FROZEN.
// 256-thr blocks (4 waves x 16 q), paired causal blocks (i,31-i) -> uniform
// 33 tile-units; 64-s tiles; dbuf global_load_lds staging w/ vmcnt(8); no
// online max (bounded inputs; exp(s-8)); bf16 O2 epilogue.
// ---------------------------------------------------------------------------
__global__ __launch_bounds__(256) void attn(
    const ushort_t* __restrict__ Q2,   // [32][2048][128]
    const ushort_t* __restrict__ K2,   // [32][2048][128]
    const ushort_t* __restrict__ V2t,  // [32][128][2048]
    ushort_t* __restrict__ O2)         // [8192][1024] bf16
{
  __shared__ i32x4 kbuf[2][1024];      // [buf][(st*4+c)*64 + lane]  16KB each
  __shared__ i32x4 vbuf[2][1024];      // [buf][(dt*2+ks)*64 + lane] 16KB each

  int bid = blockIdx.x;                      // 512 blocks
  int m   = ((bid & 7) << 2) | ((bid >> 3) & 3);  // XCD-L2 locality swizzle
  int ip  = bid >> 5;                        // pair index 0..15
  int tid = threadIdx.x;
  int w = tid >> 6, l = tid & 63;
  int lc = l & 15, lg = l >> 4;

  int iA = 31 - ip, iB = ip;
  int ntA = iA + 1;
  const int nt = 33;

  const size_t mQ = (size_t)m * 2048;
  const ushort_t* Kbase = K2  + mQ * 128;
  const ushort_t* Vbase = V2t + (size_t)m * 128 * 2048;
  int hb = m & 7, bI = m >> 3;

  int psel[4];
  #pragma unroll
  for (int w2 = 0; w2 < 4; w2++)
    psel[w2] = ((((2*(lg & 1) + (w2 >> 1)) << 4) | lc) << 2);

  auto stage = [&](int s0, int bsel){
    const ushort_t* krow = Kbase + (size_t)(s0 + w*16 + lc)*128 + 8*lg;
    #pragma unroll
    for (int c = 0; c < 4; c++)
      async_cp16(&kbuf[bsel][(w*4 + c)*64], krow + 32*c);
    #pragma unroll
    for (int j = 0; j < 4; j++){
      int dt = w*2 + (j >> 1);
      const ushort_t* vrow = Vbase + (size_t)(dt*16 + lc)*2048
                             + s0 + (j & 1)*32 + 8*lg;
      async_cp16(&vbuf[bsel][(w*4 + j)*64], vrow);
    }
  };

  int qb = iA*64 + w*16;
  bf16x8 qfrag[4];
  {
    const ushort_t* qp = Q2 + (mQ + qb + lc)*128 + 8*lg;
    #pragma unroll
    for (int c = 0; c < 4; c++) qfrag[c] = *(const bf16x8*)(qp + 32*c);
  }
  f32x4 oacc[8];
  #pragma unroll
  for (int dt = 0; dt < 8; dt++) oacc[dt] = (f32x4){0.f,0.f,0.f,0.f};
  float lrow = 0.f;

  const float LOG2E = 1.4426950408889634f;
  const float EOFF  = -11.541560327111707f;   // -8 * log2(e)

  stage(0, 0);

  for (int step = 0; step < nt; step++){
    if (step == ntA){
      // flush phase-A output
      float lt = lrow;
      lt += __shfl_xor(lt, 16);
      lt += __shfl_xor(lt, 32);
      float invl = 1.f / lt;
      size_t obase = ((size_t)(bI*2048 + qb + lc))*1024 + hb*128 + 4*lg;
      #pragma unroll
      for (int dt = 0; dt < 8; dt++){
        uint2 val;
        val.x = (unsigned)cvt_pk_bf16(oacc[dt][0]*invl, oacc[dt][1]*invl);
        val.y = (unsigned)cvt_pk_bf16(oacc[dt][2]*invl, oacc[dt][3]*invl);
        *(uint2*)&O2[obase + 16*dt] = val;
      }
      qb = iB*64 + w*16;
      const ushort_t* qp = Q2 + (mQ + qb + lc)*128 + 8*lg;
      #pragma unroll
      for (int c = 0; c < 4; c++) qfrag[c] = *(const bf16x8*)(qp + 32*c);
      #pragma unroll
      for (int dt = 0; dt < 8; dt++) oacc[dt] = (f32x4){0.f,0.f,0.f,0.f};
      lrow = 0.f;
    }
    int local = (step < ntA) ? step : step - ntA;
    bool isLast = (step == ntA - 1) || (step == nt - 1);
    int s0 = local * 64;
    int bsel = step & 1;

    if (step + 1 < nt){
      int nl = (step + 1 < ntA) ? step + 1 : step + 1 - ntA;
      stage(nl*64, bsel ^ 1);
      asm volatile("s_waitcnt vmcnt(8)\n\ts_barrier" ::: "memory");
    } else {
      asm volatile("s_waitcnt vmcnt(0)\n\ts_barrier" ::: "memory");
    }

    // ---- QK: S^T subtiles (rows = s-local, cols = q-local)
    f32x4 sacc[4];
    #pragma unroll
    for (int st = 0; st < 4; st++){
      f32x4 a2 = (f32x4){0.f,0.f,0.f,0.f};
      #pragma unroll
      for (int c = 0; c < 4; c++){
        bf16x8 kf = *(bf16x8*)&kbuf[bsel][(st*4 + c)*64 + l];
        a2 = __builtin_amdgcn_mfma_f32_16x16x32_bf16(kf, qfrag[c], a2, 0, 0, 0);
      }
      sacc[st] = a2;
    }
    if (isLast){
      int qg = qb + lc;
      #pragma unroll
      for (int st = 0; st < 4; st++)
        #pragma unroll
        for (int r = 0; r < 4; r++){
          int sg = s0 + st*16 + 4*lg + r;
          if (sg > qg) sacc[st][r] = -1e30f;
        }
    }

    // ---- p = exp(s - 8), lrow accumulated, cross-lane deferred
    float p_[4][4];
    #pragma unroll
    for (int st = 0; st < 4; st++)
      #pragma unroll
      for (int r = 0; r < 4; r++){
        float sv = fminf(fmaf(sacc[st][r], LOG2E, EOFF), 108.f);
        float pv = __builtin_amdgcn_exp2f(sv);
        p_[st][r] = pv;
        lrow += pv;
      }

    // ---- PV: O^T += V^T * P^T, two 32-s k-steps
    #pragma unroll
    for (int ks = 0; ks < 2; ks++){
      int pk0[2], pk1[2];
      #pragma unroll
      for (int pa = 0; pa < 2; pa++){
        pk0[pa] = cvt_pk_bf16(p_[2*ks][2*pa],   p_[2*ks][2*pa+1]);
        pk1[pa] = cvt_pk_bf16(p_[2*ks+1][2*pa], p_[2*ks+1][2*pa+1]);
      }
      union { int i[4]; bf16x8 v; } bfr;
      #pragma unroll
      for (int w2 = 0; w2 < 4; w2++){
        int v0 = __builtin_amdgcn_ds_bpermute(psel[w2], pk0[w2 & 1]);
        int v1 = __builtin_amdgcn_ds_bpermute(psel[w2], pk1[w2 & 1]);
        bfr.i[w2] = (lg >> 1) ? v1 : v0;
      }
      #pragma unroll
      for (int dt = 0; dt < 8; dt++){
        bf16x8 vf = *(bf16x8*)&vbuf[bsel][(dt*2 + ks)*64 + l];
        oacc[dt] = __builtin_amdgcn_mfma_f32_16x16x32_bf16(vf, bfr.v, oacc[dt], 0, 0, 0);
      }
    }
    asm volatile("s_barrier" ::: "memory");
  }

  // flush phase B
  float lt = lrow;
  lt += __shfl_xor(lt, 16);
  lt += __shfl_xor(lt, 32);
  float invl = 1.f / lt;
  size_t obase = ((size_t)(bI*2048 + qb + lc))*1024 + hb*128 + 4*lg;
  #pragma unroll
  for (int dt = 0; dt < 8; dt++){
    uint2 val;
    val.x = (unsigned)cvt_pk_bf16(oacc[dt][0]*invl, oacc[dt][1]*invl);
    val.y = (unsigned)cvt_pk_bf16(oacc[dt][2]*invl, oacc[dt][3]*invl);
    *(uint2*)&O2[obase + 16*dt] = val;
  }
}

// ---------------------------------------------------------------------------
// finalmm (MFMA): out[bt][j] = silu(bu[j] + sum_hd O2[bt][hd]*Wub[j][hd]).
// Tile 32(bt) x 128(j), K=1024 BK=32, 256 blocks (round-10 verbatim).
// ---------------------------------------------------------------------------
__global__ __launch_bounds__(256) void finalmm(
    const ushort_t* __restrict__ O2,    // [8192][1024] bf16
    const ushort_t* __restrict__ Wub,   // [128][1024] bf16
    const float* __restrict__ bu,
    float* __restrict__ out)            // [8192][128]
{
  __shared__ ushort_t As[32*32]  __attribute__((aligned(16)));   // 2 KB
  __shared__ ushort_t Bs[128*32] __attribute__((aligned(16)));   // 8 KB
  int bt0 = blockIdx.x * 32;
  int tid = threadIdx.x;
  int w = tid >> 6, ln = tid & 63;
  int lc = ln & 15, lg = ln >> 4;
  int nj = w * 32;
  int srow = ln >> 2;
  int kseg = (ln & 3) * 8;

  f32x4 acc[2][2];
  #pragma unroll
  for (int si = 0; si < 2; si++)
    #pragma unroll
    for (int sj = 0; sj < 2; sj++) acc[si][sj] = (f32x4){0.f,0.f,0.f,0.f};

  const ushort_t* gA = O2  + (size_t)(bt0 + (w & 1)*16 + srow)*1024 + kseg;
  const ushort_t* gB = Wub + (size_t)(w*32 + srow)*1024 + kseg;

  for (int kk = 0; kk < 32; kk++){
    int r0 = kk * 32;
    __syncthreads();
    if (w < 2) async_cp16(&As[w*512], gA + r0);
    async_cp16(&Bs[w*1024],       gB + r0);
    async_cp16(&Bs[w*1024 + 512], gB + r0 + 16*1024);
    __syncthreads();
    bf16x8 af[2], bfr[2];
    #pragma unroll
    for (int si = 0; si < 2; si++)
      af[si] = *(const bf16x8*)&As[(16*si + lc)*32 + 8*lg];
    #pragma unroll
    for (int sj = 0; sj < 2; sj++)
      bfr[sj] = *(const bf16x8*)&Bs[(nj + 16*sj + lc)*32 + 8*lg];
    #pragma unroll
    for (int si = 0; si < 2; si++)
      #pragma unroll
      for (int sj = 0; sj < 2; sj++)
        acc[si][sj] = __builtin_amdgcn_mfma_f32_16x16x32_bf16(af[si], bfr[sj],
                                                              acc[si][sj], 0,0,0);
  }

  float bv[2];
  #pragma unroll
  for (int sj = 0; sj < 2; sj++) bv[sj] = bu[nj + 16*sj + lc];
  #pragma unroll
  for (int si = 0; si < 2; si++)
    #pragma unroll
    for (int r = 0; r < 4; r++){
      int t = bt0 + 16*si + 4*lg + r;
      #pragma unroll
      for (int sj = 0; sj < 2; sj++)
        out[(size_t)t*128 + nj + 16*sj + lc] = silu_f(acc[si][sj][r] + bv[sj]);
    }
}

// ---------------------------------------------------------------------------
extern "C" void kernel_launch(void* const* d_in, const int* in_sizes, int n_in,
                              void* d_out, int out_size, void* d_ws, size_t ws_size,
                              hipStream_t stream) {
  const float* x  = (const float*)d_in[0];
  const float* Wq = (const float*)d_in[1];
  const float* bq = (const float*)d_in[2];
  const float* Wk = (const float*)d_in[3];
  const float* bk = (const float*)d_in[4];
  const float* Wv = (const float*)d_in[5];
  const float* Wu = (const float*)d_in[6];
  const float* bu = (const float*)d_in[7];
  float* out = (float*)d_out;

  // Workspace layout (generous slack; Xpad is 2,105,344 B)
  char* ws = (char*)d_ws;
  ushort_t* Q2   = (ushort_t*)(ws + 0);            // 16 MB
  ushort_t* K2   = (ushort_t*)(ws + 16777216);     // 16 MB
  ushort_t* V2t  = (ushort_t*)(ws + 33554432);     // 16 MB
  ushort_t* O2   = (ushort_t*)(ws + 50331648);     // 16 MB (bf16 [8192][1024])
  ushort_t* Xpad = (ushort_t*)(ws + 67108864);     // 2.008 MB
  ushort_t* W2p  = (ushort_t*)(ws + 70254592);     // 2.5 MB
  ushort_t* Wvp  = (ushort_t*)(ws + 73400320);     // 0.25 MB
  ushort_t* Wub  = (ushort_t*)(ws + 74448896);     // 0.25 MB

  prep<<<dim3(7312, 1, 1), 256, 0, stream>>>(Wq, Wk, Wv, Wu, x,
                                             W2p, Wvp, Wub, Xpad);

  gemm_qkv<<<dim3(24, 64, 1), 256, 0, stream>>>(Xpad, W2p, Wvp, bq, bk,
                                                Q2, K2, V2t);

  attn<<<dim3(512, 1, 1), 256, 0, stream>>>(Q2, K2, V2t, O2);
  finalmm<<<dim3(256, 1, 1), 256, 0, stream>>>(O2, Wub, bu, out);
}

// Round 14
// 203.874 us; speedup vs baseline: 1.4844x; 1.0130x over previous
//
#include <hip/hip_runtime.h>
#include <hip/hip_bf16.h>
#include <stdint.h>

// B=4, T=2048, K(=D)=128, H=8, KS=5, DIL=2, PAD=8, M=B*H=32
// scale = 128^0.25 ; inv = 0.29730177875068026

typedef __attribute__((ext_vector_type(8))) short bf16x8;
typedef __attribute__((ext_vector_type(4))) float f32x4;
typedef __attribute__((ext_vector_type(4))) int   i32x4;
typedef unsigned short ushort_t;

__device__ __forceinline__ unsigned short f2bf(float x){
  union{float f; unsigned u;} v; v.f = x;
  unsigned r = v.u + 0x7FFFu + ((v.u >> 16) & 1u);   // RNE
  return (unsigned short)(r >> 16);
}
__device__ __forceinline__ float silu_f(float x){ return x / (1.f + __expf(-x)); }

__device__ __forceinline__ int cvt_pk_bf16(float lo, float hi){
  int r;
  asm("v_cvt_pk_bf16_f32 %0, %1, %2" : "=v"(r) : "v"(lo), "v"(hi));
  return r;
}

__device__ __forceinline__ void async_cp16(void* lds, const void* g){
  __builtin_amdgcn_global_load_lds(
      (const __attribute__((address_space(1))) unsigned int*)g,
      (__attribute__((address_space(3))) unsigned int*)lds, 16, 0, 0);
}

// ---------------------------------------------------------------------------
// prep (round-13 verbatim).
// ---------------------------------------------------------------------------
__global__ __launch_bounds__(256) void prep(const float* __restrict__ Wq,
                                            const float* __restrict__ Wk,
                                            const float* __restrict__ Wv,
                                            const float* __restrict__ Wu,
                                            const float* __restrict__ x,
                                            ushort_t* __restrict__ W2p,
                                            ushort_t* __restrict__ Wvp,
                                            ushort_t* __restrict__ Wub,
                                            ushort_t* __restrict__ Xpad){
  int n = blockIdx.x;
  int tid = threadIdx.x;
  if (n < 2048){
    int qk = n >> 10, h = (n >> 7) & 7, d = n & 127;
    const float* src = (qk ? Wk : Wq) + (size_t)(d*8 + h)*640;
    for (int rp = tid; rp < 640; rp += 256){
      int j = rp >> 7, ci = rp & 127;
      W2p[(size_t)n*640 + rp] = f2bf(src[ci*5 + j]);
    }
  } else if (n < 3072){
    int co = n - 2048;
    for (int r = tid; r < 128; r += 256)
      Wvp[(size_t)co*128 + r] = f2bf(Wv[(size_t)co*128 + r]);
  } else if (n < 3200){
    int j = n - 3072;
    for (int r = tid; r < 1024; r += 256)
      Wub[(size_t)j*1024 + r] = f2bf(Wu[(size_t)j*1024 + r]);
  } else {
    int idx = n - 3200;              // 0..4111
    int b   = idx & 3;
    int rt  = (idx >> 2) * 2 + (tid >> 7);
    int ci  = tid & 127;
    int t   = rt - 8;
    ushort_t v = 0;
    if (t >= 0) v = f2bf(x[((size_t)(b*2048 + t))*128 + ci]);
    Xpad[((size_t)(b*2056 + rt))*128 + ci] = v;
  }
}

// ---------------------------------------------------------------------------
// gemm_qkv: merged dispatch. qk path round-13 verbatim; v path now
// DOUBLE-BUFFERED with the proven gemm_qk pattern (uniform 4 cp16/thread
// per stage -> vmcnt(4)).
// ---------------------------------------------------------------------------
__global__ __launch_bounds__(256) void gemm_qkv(
    const ushort_t* __restrict__ Xpad,  // [4][2056][128]
    const ushort_t* __restrict__ W2p,   // [2048][640]
    const ushort_t* __restrict__ Wvp,   // [1024][128]
    const float* __restrict__ bq, const float* __restrict__ bk,
    ushort_t* __restrict__ Q2, ushort_t* __restrict__ K2,
    ushort_t* __restrict__ V2t)
{
  __shared__ ushort_t As[2][128*32] __attribute__((aligned(16)));
  __shared__ ushort_t Bs[2][128*32] __attribute__((aligned(16)));
  int bt0 = blockIdx.y * 128;
  int tid = threadIdx.x;
  int w = tid >> 6, ln = tid & 63;
  int lc = ln & 15, lg = ln >> 4;
  int mi = (w & 1) * 64, nj = (w >> 1) * 64;
  int srow = ln >> 2;
  int kseg = (ln & 3) * 8;
  int b = bt0 >> 11, tl0 = bt0 & 2047;

  f32x4 acc[4][4];
  #pragma unroll
  for (int si = 0; si < 4; si++)
    #pragma unroll
    for (int sj = 0; sj < 4; sj++) acc[si][sj] = (f32x4){0.f,0.f,0.f,0.f};

  if (blockIdx.x < 16){
    // ---------------- qk path (round-13 verbatim) ----------------
    int n0 = blockIdx.x * 128;
    const ushort_t* gA = Xpad + (size_t)(b*2056 + tl0 + w*32 + srow)*128 + kseg;
    const ushort_t* gB = W2p + (size_t)(n0  + w*32 + srow)*640 + kseg;

    auto stageAB = [&](int kk, int bsel){
      int j = kk >> 2, ci0 = (kk & 3) * 32;
      int r0 = kk * 32;
      const ushort_t* a0 = gA + (size_t)(2*j)*128 + ci0;
      async_cp16(&As[bsel][w*1024],       a0);
      async_cp16(&As[bsel][w*1024 + 512], a0 + 16*128);
      async_cp16(&Bs[bsel][w*1024],       gB + r0);
      async_cp16(&Bs[bsel][w*1024 + 512], gB + r0 + 16*640);
    };

    stageAB(0, 0);
    for (int kk = 0; kk < 20; kk++){
      int bsel = kk & 1;
      if (kk + 1 < 20){
        stageAB(kk + 1, bsel ^ 1);
        asm volatile("s_waitcnt vmcnt(4)\n\ts_barrier" ::: "memory");
      } else {
        asm volatile("s_waitcnt vmcnt(0)\n\ts_barrier" ::: "memory");
      }
      bf16x8 af[4], bfr[4];
      #pragma unroll
      for (int si = 0; si < 4; si++)
        af[si] = *(const bf16x8*)&As[bsel][(mi + 16*si + lc)*32 + 8*lg];
      #pragma unroll
      for (int sj = 0; sj < 4; sj++)
        bfr[sj] = *(const bf16x8*)&Bs[bsel][(nj + 16*sj + lc)*32 + 8*lg];
      #pragma unroll
      for (int si = 0; si < 4; si++)
        #pragma unroll
        for (int sj = 0; sj < 4; sj++)
          acc[si][sj] = __builtin_amdgcn_mfma_f32_16x16x32_bf16(af[si], bfr[sj],
                                                                acc[si][sj], 0,0,0);
      asm volatile("s_barrier" ::: "memory");
    }

    const float inv_scale = 0.29730177875068026f;
    int qk = n0 >> 10, h = (n0 >> 7) & 7;
    const float* bias = qk ? bk : bq;
    ushort_t* dst = qk ? K2 : Q2;
    float bv[4];
    #pragma unroll
    for (int sj = 0; sj < 4; sj++) bv[sj] = bias[(nj + 16*sj + lc)*8 + h];

    #pragma unroll
    for (int si = 0; si < 4; si++){
      int btb = bt0 + mi + 16*si + 4*lg;
      #pragma unroll
      for (int r = 0; r < 4; r++){
        int t = btb + r;
        int bb = t >> 11, tl = t & 2047;
        size_t rowoff = ((size_t)(bb*8 + (tl >> 8))*2048 + (tl & 255)*8 + h)*128;
        #pragma unroll
        for (int sj = 0; sj < 4; sj++){
          int d = nj + 16*sj + lc;
          dst[rowoff + d] = f2bf(silu_f(acc[si][sj][r] + bv[sj]) * inv_scale);
        }
      }
    }
  } else {
    // ---------------- v path (now dbuf, proven pattern) ----------
    int n0 = (blockIdx.x - 16) * 128;
    const ushort_t* gA = Xpad + (size_t)(b*2056 + 8 + tl0 + w*32 + srow)*128 + kseg;
    const ushort_t* gB = Wvp  + (size_t)(n0 + w*32 + srow)*128 + kseg;

    auto stageV = [&](int kk, int bsel){
      int r0 = kk * 32;
      async_cp16(&As[bsel][w*1024],       gA + r0);
      async_cp16(&As[bsel][w*1024 + 512], gA + r0 + 16*128);
      async_cp16(&Bs[bsel][w*1024],       gB + r0);
      async_cp16(&Bs[bsel][w*1024 + 512], gB + r0 + 16*128);
    };

    stageV(0, 0);
    for (int kk = 0; kk < 4; kk++){
      int bsel = kk & 1;
      if (kk + 1 < 4){
        stageV(kk + 1, bsel ^ 1);
        asm volatile("s_waitcnt vmcnt(4)\n\ts_barrier" ::: "memory");
      } else {
        asm volatile("s_waitcnt vmcnt(0)\n\ts_barrier" ::: "memory");
      }
      bf16x8 af[4], bfr[4];
      #pragma unroll
      for (int si = 0; si < 4; si++)
        af[si] = *(const bf16x8*)&As[bsel][(mi + 16*si + lc)*32 + 8*lg];
      #pragma unroll
      for (int sj = 0; sj < 4; sj++)
        bfr[sj] = *(const bf16x8*)&Bs[bsel][(nj + 16*sj + lc)*32 + 8*lg];
      #pragma unroll
      for (int si = 0; si < 4; si++)
        #pragma unroll
        for (int sj = 0; sj < 4; sj++)
          acc[si][sj] = __builtin_amdgcn_mfma_f32_16x16x32_bf16(af[si], bfr[sj],
                                                                acc[si][sj], 0,0,0);
      asm volatile("s_barrier" ::: "memory");
    }

    #pragma unroll
    for (int si = 0; si < 4; si++){
      int btb = bt0 + mi + 16*si + 4*lg;
      #pragma unroll
      for (int r = 0; r < 4; r++){
        int t = btb + r;
        int bb = t >> 11, tl = t & 2047;
        int mm = bb*8 + (tl >> 8);
        int tpb = (tl & 255)*8;
        #pragma unroll
        for (int sj = 0; sj < 4; sj++){
          int co = n0 + nj + 16*sj + lc;
          int d = co >> 3, hh = co & 7;
          V2t[((size_t)mm*128 + d)*2048 + tpb + hh] = f2bf(silu_f(acc[si][sj][r]));
        }
      }
    }
  }
}

// ---------------------------------------------------------------------------
// Flash attention — EXACT round-8/10/13 kernel (passed 3x). FROZEN.
// ---------------------------------------------------------------------------
__global__ __launch_bounds__(256) void attn(
    const ushort_t* __restrict__ Q2,   // [32][2048][128]
    const ushort_t* __restrict__ K2,   // [32][2048][128]
    const ushort_t* __restrict__ V2t,  // [32][128][2048]
    ushort_t* __restrict__ O2)         // [8192][1024] bf16
{
  __shared__ i32x4 kbuf[2][1024];      // [buf][(st*4+c)*64 + lane]  16KB each
  __shared__ i32x4 vbuf[2][1024];      // [buf][(dt*2+ks)*64 + lane] 16KB each

  int bid = blockIdx.x;                      // 512 blocks
  int m   = ((bid & 7) << 2) | ((bid >> 3) & 3);  // XCD-L2 locality swizzle
  int ip  = bid >> 5;                        // pair index 0..15
  int tid = threadIdx.x;
  int w = tid >> 6, l = tid & 63;
  int lc = l & 15, lg = l >> 4;

  int iA = 31 - ip, iB = ip;
  int ntA = iA + 1;
  const int nt = 33;

  const size_t mQ = (size_t)m * 2048;
  const ushort_t* Kbase = K2  + mQ * 128;
  const ushort_t* Vbase = V2t + (size_t)m * 128 * 2048;
  int hb = m & 7, bI = m >> 3;

  int psel[4];
  #pragma unroll
  for (int w2 = 0; w2 < 4; w2++)
    psel[w2] = ((((2*(lg & 1) + (w2 >> 1)) << 4) | lc) << 2);

  auto stage = [&](int s0, int bsel){
    const ushort_t* krow = Kbase + (size_t)(s0 + w*16 + lc)*128 + 8*lg;
    #pragma unroll
    for (int c = 0; c < 4; c++)
      async_cp16(&kbuf[bsel][(w*4 + c)*64], krow + 32*c);
    #pragma unroll
    for (int j = 0; j < 4; j++){
      int dt = w*2 + (j >> 1);
      const ushort_t* vrow = Vbase + (size_t)(dt*16 + lc)*2048
                             + s0 + (j & 1)*32 + 8*lg;
      async_cp16(&vbuf[bsel][(w*4 + j)*64], vrow);
    }
  };

  int qb = iA*64 + w*16;
  bf16x8 qfrag[4];
  {
    const ushort_t* qp = Q2 + (mQ + qb + lc)*128 + 8*lg;
    #pragma unroll
    for (int c = 0; c < 4; c++) qfrag[c] = *(const bf16x8*)(qp + 32*c);
  }
  f32x4 oacc[8];
  #pragma unroll
  for (int dt = 0; dt < 8; dt++) oacc[dt] = (f32x4){0.f,0.f,0.f,0.f};
  float lrow = 0.f;

  const float LOG2E = 1.4426950408889634f;
  const float EOFF  = -11.541560327111707f;   // -8 * log2(e)

  stage(0, 0);

  for (int step = 0; step < nt; step++){
    if (step == ntA){
      float lt = lrow;
      lt += __shfl_xor(lt, 16);
      lt += __shfl_xor(lt, 32);
      float invl = 1.f / lt;
      size_t obase = ((size_t)(bI*2048 + qb + lc))*1024 + hb*128 + 4*lg;
      #pragma unroll
      for (int dt = 0; dt < 8; dt++){
        uint2 val;
        val.x = (unsigned)cvt_pk_bf16(oacc[dt][0]*invl, oacc[dt][1]*invl);
        val.y = (unsigned)cvt_pk_bf16(oacc[dt][2]*invl, oacc[dt][3]*invl);
        *(uint2*)&O2[obase + 16*dt] = val;
      }
      qb = iB*64 + w*16;
      const ushort_t* qp = Q2 + (mQ + qb + lc)*128 + 8*lg;
      #pragma unroll
      for (int c = 0; c < 4; c++) qfrag[c] = *(const bf16x8*)(qp + 32*c);
      #pragma unroll
      for (int dt = 0; dt < 8; dt++) oacc[dt] = (f32x4){0.f,0.f,0.f,0.f};
      lrow = 0.f;
    }
    int local = (step < ntA) ? step : step - ntA;
    bool isLast = (step == ntA - 1) || (step == nt - 1);
    int s0 = local * 64;
    int bsel = step & 1;

    if (step + 1 < nt){
      int nl = (step + 1 < ntA) ? step + 1 : step + 1 - ntA;
      stage(nl*64, bsel ^ 1);
      asm volatile("s_waitcnt vmcnt(8)\n\ts_barrier" ::: "memory");
    } else {
      asm volatile("s_waitcnt vmcnt(0)\n\ts_barrier" ::: "memory");
    }

    f32x4 sacc[4];
    #pragma unroll
    for (int st = 0; st < 4; st++){
      f32x4 a2 = (f32x4){0.f,0.f,0.f,0.f};
      #pragma unroll
      for (int c = 0; c < 4; c++){
        bf16x8 kf = *(bf16x8*)&kbuf[bsel][(st*4 + c)*64 + l];
        a2 = __builtin_amdgcn_mfma_f32_16x16x32_bf16(kf, qfrag[c], a2, 0, 0, 0);
      }
      sacc[st] = a2;
    }
    if (isLast){
      int qg = qb + lc;
      #pragma unroll
      for (int st = 0; st < 4; st++)
        #pragma unroll
        for (int r = 0; r < 4; r++){
          int sg = s0 + st*16 + 4*lg + r;
          if (sg > qg) sacc[st][r] = -1e30f;
        }
    }

    float p_[4][4];
    #pragma unroll
    for (int st = 0; st < 4; st++)
      #pragma unroll
      for (int r = 0; r < 4; r++){
        float sv = fminf(fmaf(sacc[st][r], LOG2E, EOFF), 108.f);
        float pv = __builtin_amdgcn_exp2f(sv);
        p_[st][r] = pv;
        lrow += pv;
      }

    #pragma unroll
    for (int ks = 0; ks < 2; ks++){
      int pk0[2], pk1[2];
      #pragma unroll
      for (int pa = 0; pa < 2; pa++){
        pk0[pa] = cvt_pk_bf16(p_[2*ks][2*pa],   p_[2*ks][2*pa+1]);
        pk1[pa] = cvt_pk_bf16(p_[2*ks+1][2*pa], p_[2*ks+1][2*pa+1]);
      }
      union { int i[4]; bf16x8 v; } bfr;
      #pragma unroll
      for (int w2 = 0; w2 < 4; w2++){
        int v0 = __builtin_amdgcn_ds_bpermute(psel[w2], pk0[w2 & 1]);
        int v1 = __builtin_amdgcn_ds_bpermute(psel[w2], pk1[w2 & 1]);
        bfr.i[w2] = (lg >> 1) ? v1 : v0;
      }
      #pragma unroll
      for (int dt = 0; dt < 8; dt++){
        bf16x8 vf = *(bf16x8*)&vbuf[bsel][(dt*2 + ks)*64 + l];
        oacc[dt] = __builtin_amdgcn_mfma_f32_16x16x32_bf16(vf, bfr.v, oacc[dt], 0, 0, 0);
      }
    }
    asm volatile("s_barrier" ::: "memory");
  }

  float lt = lrow;
  lt += __shfl_xor(lt, 16);
  lt += __shfl_xor(lt, 32);
  float invl = 1.f / lt;
  size_t obase = ((size_t)(bI*2048 + qb + lc))*1024 + hb*128 + 4*lg;
  #pragma unroll
  for (int dt = 0; dt < 8; dt++){
    uint2 val;
    val.x = (unsigned)cvt_pk_bf16(oacc[dt][0]*invl, oacc[dt][1]*invl);
    val.y = (unsigned)cvt_pk_bf16(oacc[dt][2]*invl, oacc[dt][3]*invl);
    *(uint2*)&O2[obase + 16*dt] = val;
  }
}

// ---------------------------------------------------------------------------
// finalmm (MFMA): now DOUBLE-BUFFERED. Per-thread cp16 per stage: w<2 -> 3,
// w>=2 -> 2 (non-uniform) => wait vmcnt(2): drains the older stage for both
// wave classes (w<2 also drains 1 of the newer stage — safe overdrain).
// ---------------------------------------------------------------------------
__global__ __launch_bounds__(256) void finalmm(
    const ushort_t* __restrict__ O2,    // [8192][1024] bf16
    const ushort_t* __restrict__ Wub,   // [128][1024] bf16
    const float* __restrict__ bu,
    float* __restrict__ out)            // [8192][128]
{
  __shared__ ushort_t As[2][32*32]  __attribute__((aligned(16)));   // 2x2 KB
  __shared__ ushort_t Bs[2][128*32] __attribute__((aligned(16)));   // 2x8 KB
  int bt0 = blockIdx.x * 32;
  int tid = threadIdx.x;
  int w = tid >> 6, ln = tid & 63;
  int lc = ln & 15, lg = ln >> 4;
  int nj = w * 32;
  int srow = ln >> 2;
  int kseg = (ln & 3) * 8;

  f32x4 acc[2][2];
  #pragma unroll
  for (int si = 0; si < 2; si++)
    #pragma unroll
    for (int sj = 0; sj < 2; sj++) acc[si][sj] = (f32x4){0.f,0.f,0.f,0.f};

  const ushort_t* gA = O2  + (size_t)(bt0 + (w & 1)*16 + srow)*1024 + kseg;
  const ushort_t* gB = Wub + (size_t)(w*32 + srow)*1024 + kseg;

  auto stageF = [&](int kk, int bsel){
    int r0 = kk * 32;
    if (w < 2) async_cp16(&As[bsel][w*512], gA + r0);
    async_cp16(&Bs[bsel][w*1024],       gB + r0);
    async_cp16(&Bs[bsel][w*1024 + 512], gB + r0 + 16*1024);
  };

  stageF(0, 0);
  for (int kk = 0; kk < 32; kk++){
    int bsel = kk & 1;
    if (kk + 1 < 32){
      stageF(kk + 1, bsel ^ 1);
      asm volatile("s_waitcnt vmcnt(2)\n\ts_barrier" ::: "memory");
    } else {
      asm volatile("s_waitcnt vmcnt(0)\n\ts_barrier" ::: "memory");
    }
    bf16x8 af[2], bfr[2];
    #pragma unroll
    for (int si = 0; si < 2; si++)
      af[si] = *(const bf16x8*)&As[bsel][(16*si + lc)*32 + 8*lg];
    #pragma unroll
    for (int sj = 0; sj < 2; sj++)
      bfr[sj] = *(const bf16x8*)&Bs[bsel][(nj + 16*sj + lc)*32 + 8*lg];
    #pragma unroll
    for (int si = 0; si < 2; si++)
      #pragma unroll
      for (int sj = 0; sj < 2; sj++)
        acc[si][sj] = __builtin_amdgcn_mfma_f32_16x16x32_bf16(af[si], bfr[sj],
                                                              acc[si][sj], 0,0,0);
    asm volatile("s_barrier" ::: "memory");
  }

  float bv[2];
  #pragma unroll
  for (int sj = 0; sj < 2; sj++) bv[sj] = bu[nj + 16*sj + lc];
  #pragma unroll
  for (int si = 0; si < 2; si++)
    #pragma unroll
    for (int r = 0; r < 4; r++){
      int t = bt0 + 16*si + 4*lg + r;
      #pragma unroll
      for (int sj = 0; sj < 2; sj++)
        out[(size_t)t*128 + nj + 16*sj + lc] = silu_f(acc[si][sj][r] + bv[sj]);
    }
}

// ---------------------------------------------------------------------------
extern "C" void kernel_launch(void* const* d_in, const int* in_sizes, int n_in,
                              void* d_out, int out_size, void* d_ws, size_t ws_size,
                              hipStream_t stream) {
  const float* x  = (const float*)d_in[0];
  const float* Wq = (const float*)d_in[1];
  const float* bq = (const float*)d_in[2];
  const float* Wk = (const float*)d_in[3];
  const float* bk = (const float*)d_in[4];
  const float* Wv = (const float*)d_in[5];
  const float* Wu = (const float*)d_in[6];
  const float* bu = (const float*)d_in[7];
  float* out = (float*)d_out;

  // Workspace layout (generous slack; Xpad is 2,105,344 B)
  char* ws = (char*)d_ws;
  ushort_t* Q2   = (ushort_t*)(ws + 0);            // 16 MB
  ushort_t* K2   = (ushort_t*)(ws + 16777216);     // 16 MB
  ushort_t* V2t  = (ushort_t*)(ws + 33554432);     // 16 MB
  ushort_t* O2   = (ushort_t*)(ws + 50331648);     // 16 MB (bf16 [8192][1024])
  ushort_t* Xpad = (ushort_t*)(ws + 67108864);     // 2.008 MB
  ushort_t* W2p  = (ushort_t*)(ws + 70254592);     // 2.5 MB
  ushort_t* Wvp  = (ushort_t*)(ws + 73400320);     // 0.25 MB
  ushort_t* Wub  = (ushort_t*)(ws + 74448896);     // 0.25 MB

  prep<<<dim3(7312, 1, 1), 256, 0, stream>>>(Wq, Wk, Wv, Wu, x,
                                             W2p, Wvp, Wub, Xpad);

  gemm_qkv<<<dim3(24, 64, 1), 256, 0, stream>>>(Xpad, W2p, Wvp, bq, bk,
                                                Q2, K2, V2t);

  attn<<<dim3(512, 1, 1), 256, 0, stream>>>(Q2, K2, V2t, O2);
  finalmm<<<dim3(256, 1, 1), 256, 0, stream>>>(O2, Wub, bu, out);
}

// Round 15
// 202.584 us; speedup vs baseline: 1.4938x; 1.0064x over previous
//
#include <hip/hip_runtime.h>
#include <hip/hip_bf16.h>
#include <stdint.h>

// B=4, T=2048, K(=D)=128, H=8, KS=5, DIL=2, PAD=8, M=B*H=32
// scale = 128^0.25 ; inv = 0.29730177875068026

typedef __attribute__((ext_vector_type(8))) short bf16x8;
typedef __attribute__((ext_vector_type(4))) float f32x4;
typedef __attribute__((ext_vector_type(4))) int   i32x4;
typedef unsigned short ushort_t;

__device__ __forceinline__ unsigned short f2bf(float x){
  union{float f; unsigned u;} v; v.f = x;
  unsigned r = v.u + 0x7FFFu + ((v.u >> 16) & 1u);   // RNE
  return (unsigned short)(r >> 16);
}
__device__ __forceinline__ float silu_f(float x){ return x / (1.f + __expf(-x)); }

__device__ __forceinline__ int cvt_pk_bf16(float lo, float hi){
  int r;
  asm("v_cvt_pk_bf16_f32 %0, %1, %2" : "=v"(r) : "v"(lo), "v"(hi));
  return r;
}

__device__ __forceinline__ void async_cp16(void* lds, const void* g){
  __builtin_amdgcn_global_load_lds(
      (const __attribute__((address_space(1))) unsigned int*)g,
      (__attribute__((address_space(3))) unsigned int*)lds, 16, 0, 0);
}

// ---------------------------------------------------------------------------
// prep v2: coalesced + vectorized.
//   n <  2048:        W2p row via LDS bounce (coalesced read; stride-5 LDS
//                     gather is bank-conflict-free since gcd(5,32)=1)
//   n in [2048,3072): Wvp — float4 read, packed uint2 write
//   n in [3072,3200): Wub — float4 read, packed uint2 write
//   n in [3200,4228): Xpad — 8 rows/block, float4 read, packed uint2 write
// ---------------------------------------------------------------------------
__global__ __launch_bounds__(256) void prep(const float* __restrict__ Wq,
                                            const float* __restrict__ Wk,
                                            const float* __restrict__ Wv,
                                            const float* __restrict__ Wu,
                                            const float* __restrict__ x,
                                            ushort_t* __restrict__ W2p,
                                            ushort_t* __restrict__ Wvp,
                                            ushort_t* __restrict__ Wub,
                                            ushort_t* __restrict__ Xpad){
  __shared__ float row[640];
  int n = blockIdx.x;
  int tid = threadIdx.x;
  if (n < 2048){
    int qk = n >> 10, h = (n >> 7) & 7, d = n & 127;
    const float* src = (qk ? Wk : Wq) + (size_t)(d*8 + h)*640;
    if (tid < 160) *(float4*)&row[tid*4] = *(const float4*)&src[tid*4];
    __syncthreads();
    for (int rp = tid; rp < 640; rp += 256){
      int j = rp >> 7, ci = rp & 127;
      W2p[(size_t)n*640 + rp] = f2bf(row[ci*5 + j]);
    }
  } else if (n < 3072){
    int co = n - 2048;
    if (tid < 32){
      float4 v = *(const float4*)&Wv[(size_t)co*128 + tid*4];
      uint2 pv;
      pv.x = (unsigned)cvt_pk_bf16(v.x, v.y);
      pv.y = (unsigned)cvt_pk_bf16(v.z, v.w);
      *(uint2*)&Wvp[(size_t)co*128 + tid*4] = pv;
    }
  } else if (n < 3200){
    int j = n - 3072;
    float4 v = *(const float4*)&Wu[(size_t)j*1024 + tid*4];
    uint2 pv;
    pv.x = (unsigned)cvt_pk_bf16(v.x, v.y);
    pv.y = (unsigned)cvt_pk_bf16(v.z, v.w);
    *(uint2*)&Wub[(size_t)j*1024 + tid*4] = pv;
  } else {
    int idx = n - 3200;              // 0..1027 ; 257 blocks per batch (2056=8*257)
    int b = idx / 257, rblk = idx - b*257;
    int rt = rblk*8 + (tid >> 5);
    int ci4 = (tid & 31) * 4;
    int t = rt - 8;
    uint2 val; val.x = 0u; val.y = 0u;
    if (t >= 0){
      float4 v = *(const float4*)&x[((size_t)(b*2048 + t))*128 + ci4];
      val.x = (unsigned)cvt_pk_bf16(v.x, v.y);
      val.y = (unsigned)cvt_pk_bf16(v.z, v.w);
    }
    *(uint2*)&Xpad[((size_t)(b*2056 + rt))*128 + ci4] = val;
  }
}

// ---------------------------------------------------------------------------
// gemm_qkv (round-14 verbatim): qk path dbuf vmcnt(4); v path dbuf vmcnt(4).
// ---------------------------------------------------------------------------
__global__ __launch_bounds__(256) void gemm_qkv(
    const ushort_t* __restrict__ Xpad,  // [4][2056][128]
    const ushort_t* __restrict__ W2p,   // [2048][640]
    const ushort_t* __restrict__ Wvp,   // [1024][128]
    const float* __restrict__ bq, const float* __restrict__ bk,
    ushort_t* __restrict__ Q2, ushort_t* __restrict__ K2,
    ushort_t* __restrict__ V2t)
{
  __shared__ ushort_t As[2][128*32] __attribute__((aligned(16)));
  __shared__ ushort_t Bs[2][128*32] __attribute__((aligned(16)));
  int bt0 = blockIdx.y * 128;
  int tid = threadIdx.x;
  int w = tid >> 6, ln = tid & 63;
  int lc = ln & 15, lg = ln >> 4;
  int mi = (w & 1) * 64, nj = (w >> 1) * 64;
  int srow = ln >> 2;
  int kseg = (ln & 3) * 8;
  int b = bt0 >> 11, tl0 = bt0 & 2047;

  f32x4 acc[4][4];
  #pragma unroll
  for (int si = 0; si < 4; si++)
    #pragma unroll
    for (int sj = 0; sj < 4; sj++) acc[si][sj] = (f32x4){0.f,0.f,0.f,0.f};

  if (blockIdx.x < 16){
    int n0 = blockIdx.x * 128;
    const ushort_t* gA = Xpad + (size_t)(b*2056 + tl0 + w*32 + srow)*128 + kseg;
    const ushort_t* gB = W2p + (size_t)(n0  + w*32 + srow)*640 + kseg;

    auto stageAB = [&](int kk, int bsel){
      int j = kk >> 2, ci0 = (kk & 3) * 32;
      int r0 = kk * 32;
      const ushort_t* a0 = gA + (size_t)(2*j)*128 + ci0;
      async_cp16(&As[bsel][w*1024],       a0);
      async_cp16(&As[bsel][w*1024 + 512], a0 + 16*128);
      async_cp16(&Bs[bsel][w*1024],       gB + r0);
      async_cp16(&Bs[bsel][w*1024 + 512], gB + r0 + 16*640);
    };

    stageAB(0, 0);
    for (int kk = 0; kk < 20; kk++){
      int bsel = kk & 1;
      if (kk + 1 < 20){
        stageAB(kk + 1, bsel ^ 1);
        asm volatile("s_waitcnt vmcnt(4)\n\ts_barrier" ::: "memory");
      } else {
        asm volatile("s_waitcnt vmcnt(0)\n\ts_barrier" ::: "memory");
      }
      bf16x8 af[4], bfr[4];
      #pragma unroll
      for (int si = 0; si < 4; si++)
        af[si] = *(const bf16x8*)&As[bsel][(mi + 16*si + lc)*32 + 8*lg];
      #pragma unroll
      for (int sj = 0; sj < 4; sj++)
        bfr[sj] = *(const bf16x8*)&Bs[bsel][(nj + 16*sj + lc)*32 + 8*lg];
      #pragma unroll
      for (int si = 0; si < 4; si++)
        #pragma unroll
        for (int sj = 0; sj < 4; sj++)
          acc[si][sj] = __builtin_amdgcn_mfma_f32_16x16x32_bf16(af[si], bfr[sj],
                                                                acc[si][sj], 0,0,0);
      asm volatile("s_barrier" ::: "memory");
    }

    const float inv_scale = 0.29730177875068026f;
    int qk = n0 >> 10, h = (n0 >> 7) & 7;
    const float* bias = qk ? bk : bq;
    ushort_t* dst = qk ? K2 : Q2;
    float bv[4];
    #pragma unroll
    for (int sj = 0; sj < 4; sj++) bv[sj] = bias[(nj + 16*sj + lc)*8 + h];

    #pragma unroll
    for (int si = 0; si < 4; si++){
      int btb = bt0 + mi + 16*si + 4*lg;
      #pragma unroll
      for (int r = 0; r < 4; r++){
        int t = btb + r;
        int bb = t >> 11, tl = t & 2047;
        size_t rowoff = ((size_t)(bb*8 + (tl >> 8))*2048 + (tl & 255)*8 + h)*128;
        #pragma unroll
        for (int sj = 0; sj < 4; sj++){
          int d = nj + 16*sj + lc;
          dst[rowoff + d] = f2bf(silu_f(acc[si][sj][r] + bv[sj]) * inv_scale);
        }
      }
    }
  } else {
    int n0 = (blockIdx.x - 16) * 128;
    const ushort_t* gA = Xpad + (size_t)(b*2056 + 8 + tl0 + w*32 + srow)*128 + kseg;
    const ushort_t* gB = Wvp  + (size_t)(n0 + w*32 + srow)*128 + kseg;

    auto stageV = [&](int kk, int bsel){
      int r0 = kk * 32;
      async_cp16(&As[bsel][w*1024],       gA + r0);
      async_cp16(&As[bsel][w*1024 + 512], gA + r0 + 16*128);
      async_cp16(&Bs[bsel][w*1024],       gB + r0);
      async_cp16(&Bs[bsel][w*1024 + 512], gB + r0 + 16*128);
    };

    stageV(0, 0);
    for (int kk = 0; kk < 4; kk++){
      int bsel = kk & 1;
      if (kk + 1 < 4){
        stageV(kk + 1, bsel ^ 1);
        asm volatile("s_waitcnt vmcnt(4)\n\ts_barrier" ::: "memory");
      } else {
        asm volatile("s_waitcnt vmcnt(0)\n\ts_barrier" ::: "memory");
      }
      bf16x8 af[4], bfr[4];
      #pragma unroll
      for (int si = 0; si < 4; si++)
        af[si] = *(const bf16x8*)&As[bsel][(mi + 16*si + lc)*32 + 8*lg];
      #pragma unroll
      for (int sj = 0; sj < 4; sj++)
        bfr[sj] = *(const bf16x8*)&Bs[bsel][(nj + 16*sj + lc)*32 + 8*lg];
      #pragma unroll
      for (int si = 0; si < 4; si++)
        #pragma unroll
        for (int sj = 0; sj < 4; sj++)
          acc[si][sj] = __builtin_amdgcn_mfma_f32_16x16x32_bf16(af[si], bfr[sj],
                                                                acc[si][sj], 0,0,0);
      asm volatile("s_barrier" ::: "memory");
    }

    #pragma unroll
    for (int si = 0; si < 4; si++){
      int btb = bt0 + mi + 16*si + 4*lg;
      #pragma unroll
      for (int r = 0; r < 4; r++){
        int t = btb + r;
        int bb = t >> 11, tl = t & 2047;
        int mm = bb*8 + (tl >> 8);
        int tpb = (tl & 255)*8;
        #pragma unroll
        for (int sj = 0; sj < 4; sj++){
          int co = n0 + nj + 16*sj + lc;
          int d = co >> 3, hh = co & 7;
          V2t[((size_t)mm*128 + d)*2048 + tpb + hh] = f2bf(silu_f(acc[si][sj][r]));
        }
      }
    }
  }
}

// ---------------------------------------------------------------------------
// Flash attention — EXACT round-8/10/13/14 kernel (passed 4x). FROZEN.
// ---------------------------------------------------------------------------
__global__ __launch_bounds__(256) void attn(
    const ushort_t* __restrict__ Q2,   // [32][2048][128]
    const ushort_t* __restrict__ K2,   // [32][2048][128]
    const ushort_t* __restrict__ V2t,  // [32][128][2048]
    ushort_t* __restrict__ O2)         // [8192][1024] bf16
{
  __shared__ i32x4 kbuf[2][1024];      // [buf][(st*4+c)*64 + lane]  16KB each
  __shared__ i32x4 vbuf[2][1024];      // [buf][(dt*2+ks)*64 + lane] 16KB each

  int bid = blockIdx.x;                      // 512 blocks
  int m   = ((bid & 7) << 2) | ((bid >> 3) & 3);  // XCD-L2 locality swizzle
  int ip  = bid >> 5;                        // pair index 0..15
  int tid = threadIdx.x;
  int w = tid >> 6, l = tid & 63;
  int lc = l & 15, lg = l >> 4;

  int iA = 31 - ip, iB = ip;
  int ntA = iA + 1;
  const int nt = 33;

  const size_t mQ = (size_t)m * 2048;
  const ushort_t* Kbase = K2  + mQ * 128;
  const ushort_t* Vbase = V2t + (size_t)m * 128 * 2048;
  int hb = m & 7, bI = m >> 3;

  int psel[4];
  #pragma unroll
  for (int w2 = 0; w2 < 4; w2++)
    psel[w2] = ((((2*(lg & 1) + (w2 >> 1)) << 4) | lc) << 2);

  auto stage = [&](int s0, int bsel){
    const ushort_t* krow = Kbase + (size_t)(s0 + w*16 + lc)*128 + 8*lg;
    #pragma unroll
    for (int c = 0; c < 4; c++)
      async_cp16(&kbuf[bsel][(w*4 + c)*64], krow + 32*c);
    #pragma unroll
    for (int j = 0; j < 4; j++){
      int dt = w*2 + (j >> 1);
      const ushort_t* vrow = Vbase + (size_t)(dt*16 + lc)*2048
                             + s0 + (j & 1)*32 + 8*lg;
      async_cp16(&vbuf[bsel][(w*4 + j)*64], vrow);
    }
  };

  int qb = iA*64 + w*16;
  bf16x8 qfrag[4];
  {
    const ushort_t* qp = Q2 + (mQ + qb + lc)*128 + 8*lg;
    #pragma unroll
    for (int c = 0; c < 4; c++) qfrag[c] = *(const bf16x8*)(qp + 32*c);
  }
  f32x4 oacc[8];
  #pragma unroll
  for (int dt = 0; dt < 8; dt++) oacc[dt] = (f32x4){0.f,0.f,0.f,0.f};
  float lrow = 0.f;

  const float LOG2E = 1.4426950408889634f;
  const float EOFF  = -11.541560327111707f;   // -8 * log2(e)

  stage(0, 0);

  for (int step = 0; step < nt; step++){
    if (step == ntA){
      float lt = lrow;
      lt += __shfl_xor(lt, 16);
      lt += __shfl_xor(lt, 32);
      float invl = 1.f / lt;
      size_t obase = ((size_t)(bI*2048 + qb + lc))*1024 + hb*128 + 4*lg;
      #pragma unroll
      for (int dt = 0; dt < 8; dt++){
        uint2 val;
        val.x = (unsigned)cvt_pk_bf16(oacc[dt][0]*invl, oacc[dt][1]*invl);
        val.y = (unsigned)cvt_pk_bf16(oacc[dt][2]*invl, oacc[dt][3]*invl);
        *(uint2*)&O2[obase + 16*dt] = val;
      }
      qb = iB*64 + w*16;
      const ushort_t* qp = Q2 + (mQ + qb + lc)*128 + 8*lg;
      #pragma unroll
      for (int c = 0; c < 4; c++) qfrag[c] = *(const bf16x8*)(qp + 32*c);
      #pragma unroll
      for (int dt = 0; dt < 8; dt++) oacc[dt] = (f32x4){0.f,0.f,0.f,0.f};
      lrow = 0.f;
    }
    int local = (step < ntA) ? step : step - ntA;
    bool isLast = (step == ntA - 1) || (step == nt - 1);
    int s0 = local * 64;
    int bsel = step & 1;

    if (step + 1 < nt){
      int nl = (step + 1 < ntA) ? step + 1 : step + 1 - ntA;
      stage(nl*64, bsel ^ 1);
      asm volatile("s_waitcnt vmcnt(8)\n\ts_barrier" ::: "memory");
    } else {
      asm volatile("s_waitcnt vmcnt(0)\n\ts_barrier" ::: "memory");
    }

    f32x4 sacc[4];
    #pragma unroll
    for (int st = 0; st < 4; st++){
      f32x4 a2 = (f32x4){0.f,0.f,0.f,0.f};
      #pragma unroll
      for (int c = 0; c < 4; c++){
        bf16x8 kf = *(bf16x8*)&kbuf[bsel][(st*4 + c)*64 + l];
        a2 = __builtin_amdgcn_mfma_f32_16x16x32_bf16(kf, qfrag[c], a2, 0, 0, 0);
      }
      sacc[st] = a2;
    }
    if (isLast){
      int qg = qb + lc;
      #pragma unroll
      for (int st = 0; st < 4; st++)
        #pragma unroll
        for (int r = 0; r < 4; r++){
          int sg = s0 + st*16 + 4*lg + r;
          if (sg > qg) sacc[st][r] = -1e30f;
        }
    }

    float p_[4][4];
    #pragma unroll
    for (int st = 0; st < 4; st++)
      #pragma unroll
      for (int r = 0; r < 4; r++){
        float sv = fminf(fmaf(sacc[st][r], LOG2E, EOFF), 108.f);
        float pv = __builtin_amdgcn_exp2f(sv);
        p_[st][r] = pv;
        lrow += pv;
      }

    #pragma unroll
    for (int ks = 0; ks < 2; ks++){
      int pk0[2], pk1[2];
      #pragma unroll
      for (int pa = 0; pa < 2; pa++){
        pk0[pa] = cvt_pk_bf16(p_[2*ks][2*pa],   p_[2*ks][2*pa+1]);
        pk1[pa] = cvt_pk_bf16(p_[2*ks+1][2*pa], p_[2*ks+1][2*pa+1]);
      }
      union { int i[4]; bf16x8 v; } bfr;
      #pragma unroll
      for (int w2 = 0; w2 < 4; w2++){
        int v0 = __builtin_amdgcn_ds_bpermute(psel[w2], pk0[w2 & 1]);
        int v1 = __builtin_amdgcn_ds_bpermute(psel[w2], pk1[w2 & 1]);
        bfr.i[w2] = (lg >> 1) ? v1 : v0;
      }
      #pragma unroll
      for (int dt = 0; dt < 8; dt++){
        bf16x8 vf = *(bf16x8*)&vbuf[bsel][(dt*2 + ks)*64 + l];
        oacc[dt] = __builtin_amdgcn_mfma_f32_16x16x32_bf16(vf, bfr.v, oacc[dt], 0, 0, 0);
      }
    }
    asm volatile("s_barrier" ::: "memory");
  }

  float lt = lrow;
  lt += __shfl_xor(lt, 16);
  lt += __shfl_xor(lt, 32);
  float invl = 1.f / lt;
  size_t obase = ((size_t)(bI*2048 + qb + lc))*1024 + hb*128 + 4*lg;
  #pragma unroll
  for (int dt = 0; dt < 8; dt++){
    uint2 val;
    val.x = (unsigned)cvt_pk_bf16(oacc[dt][0]*invl, oacc[dt][1]*invl);
    val.y = (unsigned)cvt_pk_bf16(oacc[dt][2]*invl, oacc[dt][3]*invl);
    *(uint2*)&O2[obase + 16*dt] = val;
  }
}

// ---------------------------------------------------------------------------
// finalmm (round-14 verbatim): dbuf, vmcnt(2).
// ---------------------------------------------------------------------------
__global__ __launch_bounds__(256) void finalmm(
    const ushort_t* __restrict__ O2,    // [8192][1024] bf16
    const ushort_t* __restrict__ Wub,   // [128][1024] bf16
    const float* __restrict__ bu,
    float* __restrict__ out)            // [8192][128]
{
  __shared__ ushort_t As[2][32*32]  __attribute__((aligned(16)));   // 2x2 KB
  __shared__ ushort_t Bs[2][128*32] __attribute__((aligned(16)));   // 2x8 KB
  int bt0 = blockIdx.x * 32;
  int tid = threadIdx.x;
  int w = tid >> 6, ln = tid & 63;
  int lc = ln & 15, lg = ln >> 4;
  int nj = w * 32;
  int srow = ln >> 2;
  int kseg = (ln & 3) * 8;

  f32x4 acc[2][2];
  #pragma unroll
  for (int si = 0; si < 2; si++)
    #pragma unroll
    for (int sj = 0; sj < 2; sj++) acc[si][sj] = (f32x4){0.f,0.f,0.f,0.f};

  const ushort_t* gA = O2  + (size_t)(bt0 + (w & 1)*16 + srow)*1024 + kseg;
  const ushort_t* gB = Wub + (size_t)(w*32 + srow)*1024 + kseg;

  auto stageF = [&](int kk, int bsel){
    int r0 = kk * 32;
    if (w < 2) async_cp16(&As[bsel][w*512], gA + r0);
    async_cp16(&Bs[bsel][w*1024],       gB + r0);
    async_cp16(&Bs[bsel][w*1024 + 512], gB + r0 + 16*1024);
  };

  stageF(0, 0);
  for (int kk = 0; kk < 32; kk++){
    int bsel = kk & 1;
    if (kk + 1 < 32){
      stageF(kk + 1, bsel ^ 1);
      asm volatile("s_waitcnt vmcnt(2)\n\ts_barrier" ::: "memory");
    } else {
      asm volatile("s_waitcnt vmcnt(0)\n\ts_barrier" ::: "memory");
    }
    bf16x8 af[2], bfr[2];
    #pragma unroll
    for (int si = 0; si < 2; si++)
      af[si] = *(const bf16x8*)&As[bsel][(16*si + lc)*32 + 8*lg];
    #pragma unroll
    for (int sj = 0; sj < 2; sj++)
      bfr[sj] = *(const bf16x8*)&Bs[bsel][(nj + 16*sj + lc)*32 + 8*lg];
    #pragma unroll
    for (int si = 0; si < 2; si++)
      #pragma unroll
      for (int sj = 0; sj < 2; sj++)
        acc[si][sj] = __builtin_amdgcn_mfma_f32_16x16x32_bf16(af[si], bfr[sj],
                                                              acc[si][sj], 0,0,0);
    asm volatile("s_barrier" ::: "memory");
  }

  float bv[2];
  #pragma unroll
  for (int sj = 0; sj < 2; sj++) bv[sj] = bu[nj + 16*sj + lc];
  #pragma unroll
  for (int si = 0; si < 2; si++)
    #pragma unroll
    for (int r = 0; r < 4; r++){
      int t = bt0 + 16*si + 4*lg + r;
      #pragma unroll
      for (int sj = 0; sj < 2; sj++)
        out[(size_t)t*128 + nj + 16*sj + lc] = silu_f(acc[si][sj][r] + bv[sj]);
    }
}

// ---------------------------------------------------------------------------
extern "C" void kernel_launch(void* const* d_in, const int* in_sizes, int n_in,
                              void* d_out, int out_size, void* d_ws, size_t ws_size,
                              hipStream_t stream) {
  const float* x  = (const float*)d_in[0];
  const float* Wq = (const float*)d_in[1];
  const float* bq = (const float*)d_in[2];
  const float* Wk = (const float*)d_in[3];
  const float* bk = (const float*)d_in[4];
  const float* Wv = (const float*)d_in[5];
  const float* Wu = (const float*)d_in[6];
  const float* bu = (const float*)d_in[7];
  float* out = (float*)d_out;

  // Workspace layout (generous slack; Xpad is 2,105,344 B)
  char* ws = (char*)d_ws;
  ushort_t* Q2   = (ushort_t*)(ws + 0);            // 16 MB
  ushort_t* K2   = (ushort_t*)(ws + 16777216);     // 16 MB
  ushort_t* V2t  = (ushort_t*)(ws + 33554432);     // 16 MB
  ushort_t* O2   = (ushort_t*)(ws + 50331648);     // 16 MB (bf16 [8192][1024])
  ushort_t* Xpad = (ushort_t*)(ws + 67108864);     // 2.008 MB
  ushort_t* W2p  = (ushort_t*)(ws + 70254592);     // 2.5 MB
  ushort_t* Wvp  = (ushort_t*)(ws + 73400320);     // 0.25 MB
  ushort_t* Wub  = (ushort_t*)(ws + 74448896);     // 0.25 MB

  prep<<<dim3(4228, 1, 1), 256, 0, stream>>>(Wq, Wk, Wv, Wu, x,
                                             W2p, Wvp, Wub, Xpad);

  gemm_qkv<<<dim3(24, 64, 1), 256, 0, stream>>>(Xpad, W2p, Wvp, bq, bk,
                                                Q2, K2, V2t);

  attn<<<dim3(512, 1, 1), 256, 0, stream>>>(Q2, K2, V2t, O2);
  finalmm<<<dim3(256, 1, 1), 256, 0, stream>>>(O2, Wub, bu, out);
}